// Round 1
// baseline (3272.496 us; speedup 1.0000x reference)
//
#include <hip/hip_runtime.h>

#define TTOK 8192   // B*L
#define BATCH 4
#define LSEQ 2048
#define NDM 256
#define NF 128
#define NDI 512
#define NDS 16
#define NDR 16

__device__ __forceinline__ float sigmoidf_(float x) { return 1.f / (1.f + __expf(-x)); }

// C[m,n] = act(sum_k A[m,k]*W[n,k] + bias[n]) [+= if RES]
// A: (M, lda) row-major. W: (N, Kd) row-major. M must be multiple of BM.
template<int BM, int BN, int BK, int ACT, bool BIAS, bool RES, bool NCHK>
__global__ __launch_bounds__(256) void gemm_tn(const float* __restrict__ A, int lda,
                                               const float* __restrict__ W,
                                               const float* __restrict__ bias,
                                               float* __restrict__ C, int ldc,
                                               int N, int Kd) {
  constexpr int TM = BM / 16, TN = BN / 16;
  __shared__ float As[BK][BM + 4];
  __shared__ float Ws[BK][BN + 4];
  const int tid = threadIdx.x;
  const int tx = tid & 15, ty = tid >> 4;
  const int row0 = blockIdx.y * BM;
  const int col0 = blockIdx.x * BN;
  float acc[TM][TN] = {};
  for (int k0 = 0; k0 < Kd; k0 += BK) {
    for (int idx = tid; idx < BM * BK / 4; idx += 256) {
      int r = (idx << 2) / BK, kk = (idx << 2) % BK;
      float4 v = *(const float4*)(A + (long)(row0 + r) * lda + k0 + kk);
      As[kk + 0][r] = v.x; As[kk + 1][r] = v.y; As[kk + 2][r] = v.z; As[kk + 3][r] = v.w;
    }
    for (int idx = tid; idx < BN * BK / 4; idx += 256) {
      int r = (idx << 2) / BK, kk = (idx << 2) % BK;
      float4 v = make_float4(0.f, 0.f, 0.f, 0.f);
      if (!NCHK || (col0 + r) < N) v = *(const float4*)(W + (long)(col0 + r) * Kd + k0 + kk);
      Ws[kk + 0][r] = v.x; Ws[kk + 1][r] = v.y; Ws[kk + 2][r] = v.z; Ws[kk + 3][r] = v.w;
    }
    __syncthreads();
#pragma unroll
    for (int k = 0; k < BK; ++k) {
      float a[TM], w[TN];
#pragma unroll
      for (int i = 0; i < TM; i += 4) *(float4*)(a + i) = *(const float4*)(&As[k][ty * TM + i]);
#pragma unroll
      for (int j = 0; j < TN; j += 4) *(float4*)(w + j) = *(const float4*)(&Ws[k][tx * TN + j]);
#pragma unroll
      for (int i = 0; i < TM; ++i)
#pragma unroll
        for (int j = 0; j < TN; ++j) acc[i][j] = fmaf(a[i], w[j], acc[i][j]);
    }
    __syncthreads();
  }
#pragma unroll
  for (int i = 0; i < TM; ++i) {
    int r = row0 + ty * TM + i;
#pragma unroll
    for (int j = 0; j < TN; ++j) {
      int c = col0 + tx * TN + j;
      if (NCHK && c >= N) continue;
      float v = acc[i][j];
      if (BIAS) v += bias[c];
      if (ACT == 1) v = fmaxf(v, 0.f) + log1pf(__expf(-fabsf(v)));  // softplus, stable
      float* p = C + (long)r * ldc + c;
      if (RES) *p += v; else *p = v;
    }
  }
}

__global__ __launch_bounds__(256) void rmsnorm_k(const float* __restrict__ h,
                                                 const float* __restrict__ w,
                                                 float* __restrict__ o) {
  const int t = blockIdx.x, d = threadIdx.x;
  float v = h[t * NDM + d];
  float s = v * v;
#pragma unroll
  for (int off = 32; off >= 1; off >>= 1) s += __shfl_xor(s, off);
  __shared__ float red[4];
  if ((d & 63) == 0) red[d >> 6] = s;
  __syncthreads();
  float tot = red[0] + red[1] + red[2] + red[3];
  o[t * NDM + d] = v * rsqrtf(tot * (1.f / NDM) + 1e-6f) * w[d];
}

// u2 = silu(depthwise causal conv(u)), u = xz[:, :512]
__global__ __launch_bounds__(256) void conv_silu_k(const float* __restrict__ xz,
                                                   const float* __restrict__ cw,
                                                   const float* __restrict__ cb,
                                                   float* __restrict__ u2) {
  const int t = blockIdx.x, l = t & (LSEQ - 1);
#pragma unroll
  for (int half = 0; half < 2; ++half) {
    const int c = threadIdx.x + half * 256;
    float acc = cb[c];
#pragma unroll
    for (int k = 0; k < 4; ++k) {
      int lp = l - 3 + k;
      if (lp >= 0) acc = fmaf(xz[(t - 3 + k) * 1024 + c], cw[c * 4 + k], acc);
    }
    u2[t * NDI + c] = acc * sigmoidf_(acc);
  }
}

// Fused selective scan + C-contraction + u*D + silu(z) gating.
// 16 lanes per (b,d) chain, one lane per state n.
__global__ __launch_bounds__(64) void scan_k(const float* __restrict__ delta,
                                             const float* __restrict__ u2,
                                             const float* __restrict__ dbc,
                                             const float* __restrict__ xz,
                                             const float* __restrict__ Alog,
                                             const float* __restrict__ Dp,
                                             float* __restrict__ y) {
  const int grp = threadIdx.x >> 4, n = threadIdx.x & 15;
  const int chain = blockIdx.x * 4 + grp;
  const int b = chain >> 9, d = chain & (NDI - 1);
  const float Acoef = -__expf(Alog[d * NDS + n]);
  const float Dv = Dp[d];
  float state = 0.f;
  const int tbase = b * LSEQ;
  for (int l = 0; l < LSEQ; ++l) {
    const int t = tbase + l;
    float dl = delta[t * NDI + d];
    float ul = u2[t * NDI + d];
    float Bn = dbc[t * 48 + NDR + n];
    float Cn = dbc[t * 48 + NDR + NDS + n];
    float dA = __expf(dl * Acoef);
    state = fmaf(dA, state, dl * ul * Bn);
    float p = state * Cn;
    p += __shfl_xor(p, 1); p += __shfl_xor(p, 2);
    p += __shfl_xor(p, 4); p += __shfl_xor(p, 8);
    if (n == 0) {
      float zl = xz[t * 1024 + NDI + d];
      y[t * NDI + d] = (p + ul * Dv) * zl * sigmoidf_(zl);
    }
  }
}

__global__ __launch_bounds__(256) void pool_k(const float* __restrict__ hn,
                                              float* __restrict__ pooled) {
  const int b = blockIdx.y, d = threadIdx.x;
  const int base = b * LSEQ + blockIdx.x * 128;
  float acc = 0.f;
  for (int j = 0; j < 128; ++j) acc += hn[(base + j) * NDM + d];
  atomicAdd(pooled + b * NDM + d, acc * (1.f / LSEQ));
}

__global__ __launch_bounds__(128) void bias_k(const float* __restrict__ pooled,
                                              const float* __restrict__ pw,
                                              const float* __restrict__ pb,
                                              float* __restrict__ bv) {
  const int b = blockIdx.x, f = threadIdx.x;
  float acc = pb[f];
  for (int dd = 0; dd < NDM; ++dd) acc = fmaf(pooled[b * NDM + dd], pw[f * NDM + dd], acc);
  bv[b * NF + f] = acc;
}

__global__ __launch_bounds__(256) void addout_k(const float* __restrict__ x,
                                                const float* __restrict__ bv,
                                                float* __restrict__ out) {
  const int i4 = blockIdx.x * 256 + threadIdx.x;  // 262144 float4 total
  const float4 xv = ((const float4*)x)[i4];
  const int trow = i4 >> 5;      // 32 float4 per 128-wide row
  const int b = trow >> 11;      // 2048 rows per batch
  const int f4 = i4 & 31;
  const float4 bb = ((const float4*)bv)[b * 32 + f4];
  float4 o;
  o.x = xv.x + bb.x; o.y = xv.y + bb.y; o.z = xv.z + bb.z; o.w = xv.w + bb.w;
  ((float4*)out)[i4] = o;
}

extern "C" void kernel_launch(void* const* d_in, const int* in_sizes, int n_in,
                              void* d_out, int out_size, void* d_ws, size_t ws_size,
                              hipStream_t stream) {
  const float* x       = (const float*)d_in[0];
  const float* embed_w = (const float*)d_in[1];
  const float* embed_b = (const float*)d_in[2];
  const float* in_w    = (const float*)d_in[3];
  const float* conv_w  = (const float*)d_in[4];
  const float* conv_b  = (const float*)d_in[5];
  const float* xproj_w = (const float*)d_in[6];
  const float* dt_w    = (const float*)d_in[7];
  const float* dt_b    = (const float*)d_in[8];
  const float* A_log   = (const float*)d_in[9];
  const float* Dw      = (const float*)d_in[10];
  const float* out_w   = (const float*)d_in[11];
  const float* norm_w  = (const float*)d_in[12];
  const float* fnorm_w = (const float*)d_in[13];
  const float* proj_w  = (const float*)d_in[14];
  const float* proj_b  = (const float*)d_in[15];

  // workspace layout (floats), total ~97.5 MB
  float* ws     = (float*)d_ws;
  float* h      = ws;                           // 8192*256
  float* hn     = h     + (long)TTOK * NDM;     // 8192*256
  float* xz     = hn    + (long)TTOK * NDM;     // 8192*1024 (u | z)
  float* u2     = xz    + (long)TTOK * 1024;    // 8192*512
  float* dbc    = u2    + (long)TTOK * NDI;     // 8192*48  (dt | B | C)
  float* delta  = dbc   + (long)TTOK * 48;      // 8192*512
  float* yb     = delta + (long)TTOK * NDI;     // 8192*512
  float* pooled = yb    + (long)TTOK * NDI;     // 4*256
  float* bv     = pooled + BATCH * NDM;         // 4*128

  // h = x @ embed_w^T + embed_b
  gemm_tn<64, 64, 16, 0, true, false, false><<<dim3(NDM / 64, TTOK / 64), 256, 0, stream>>>(
      x, NF, embed_w, embed_b, h, NDM, NDM, NF);

  for (int i = 0; i < 2; ++i) {
    const float* inw = in_w    + (long)i * 2 * NDI * NDM;
    const float* cw  = conv_w  + (long)i * NDI * 4;
    const float* cb  = conv_b  + (long)i * NDI;
    const float* xpw = xproj_w + (long)i * 48 * NDI;
    const float* dtw = dt_w    + (long)i * NDI * NDR;
    const float* dtb = dt_b    + (long)i * NDI;
    const float* al  = A_log   + (long)i * NDI * NDS;
    const float* dd  = Dw      + (long)i * NDI;
    const float* ow  = out_w   + (long)i * NDM * NDI;

    rmsnorm_k<<<TTOK, 256, 0, stream>>>(h, norm_w + i * NDM, hn);
    // xz = hn @ in_w^T   (8192 x 1024 x 256)
    gemm_tn<128, 128, 16, 0, false, false, false><<<dim3(1024 / 128, TTOK / 128), 256, 0, stream>>>(
        hn, NDM, inw, nullptr, xz, 1024, 1024, NDM);
    conv_silu_k<<<TTOK, 256, 0, stream>>>(xz, cw, cb, u2);
    // dbc = u2 @ xproj_w^T  (8192 x 48 x 512)
    gemm_tn<64, 64, 16, 0, false, false, true><<<dim3(1, TTOK / 64), 256, 0, stream>>>(
        u2, NDI, xpw, nullptr, dbc, 48, 48, NDI);
    // delta = softplus(dt @ dt_w^T + dt_b)  (8192 x 512 x 16)
    gemm_tn<64, 64, 16, 1, true, false, false><<<dim3(NDI / 64, TTOK / 64), 256, 0, stream>>>(
        dbc, 48, dtw, dtb, delta, NDI, NDI, NDR);
    scan_k<<<512, 64, 0, stream>>>(delta, u2, dbc, xz, al, dd, yb);
    // h += yb @ out_w^T   (8192 x 256 x 512)
    gemm_tn<64, 64, 16, 0, false, true, false><<<dim3(NDM / 64, TTOK / 64), 256, 0, stream>>>(
        yb, NDI, ow, nullptr, h, NDM, NDM, NDI);
  }

  rmsnorm_k<<<TTOK, 256, 0, stream>>>(h, fnorm_w, hn);
  hipMemsetAsync(pooled, 0, BATCH * NDM * sizeof(float), stream);
  pool_k<<<dim3(LSEQ / 128, BATCH), 256, 0, stream>>>(hn, pooled);
  bias_k<<<BATCH, 128, 0, stream>>>(pooled, proj_w, proj_b, bv);
  addout_k<<<TTOK * NF / 4 / 256, 256, 0, stream>>>(x, bv, (float*)d_out);
}

// Round 2
// 677.348 us; speedup vs baseline: 4.8313x; 4.8313x over previous
//
#include <hip/hip_runtime.h>

#define TTOK 8192   // B*L
#define BATCH 4
#define LSEQ 2048
#define NDM 256
#define NF 128
#define NDI 512
#define NDS 16
#define NDR 16
#define CHUNK 128
#define NCH (LSEQ / CHUNK)   // 16

__device__ __forceinline__ float sigmoidf_(float x) { return 1.f / (1.f + __expf(-x)); }

// C[m,n] = act(sum_k A[m,k]*W[n,k] + bias[n]) [+= if RES]
// A: (M, lda) row-major. W: (N, Kd) row-major. M must be multiple of BM.
template<int BM, int BN, int BK, int ACT, bool BIAS, bool RES, bool NCHK>
__global__ __launch_bounds__(256) void gemm_tn(const float* __restrict__ A, int lda,
                                               const float* __restrict__ W,
                                               const float* __restrict__ bias,
                                               float* __restrict__ C, int ldc,
                                               int N, int Kd) {
  constexpr int TM = BM / 16, TN = BN / 16;
  __shared__ float As[BK][BM + 4];
  __shared__ float Ws[BK][BN + 4];
  const int tid = threadIdx.x;
  const int tx = tid & 15, ty = tid >> 4;
  const int row0 = blockIdx.y * BM;
  const int col0 = blockIdx.x * BN;
  float acc[TM][TN] = {};
  for (int k0 = 0; k0 < Kd; k0 += BK) {
    for (int idx = tid; idx < BM * BK / 4; idx += 256) {
      int r = (idx << 2) / BK, kk = (idx << 2) % BK;
      float4 v = *(const float4*)(A + (long)(row0 + r) * lda + k0 + kk);
      As[kk + 0][r] = v.x; As[kk + 1][r] = v.y; As[kk + 2][r] = v.z; As[kk + 3][r] = v.w;
    }
    for (int idx = tid; idx < BN * BK / 4; idx += 256) {
      int r = (idx << 2) / BK, kk = (idx << 2) % BK;
      float4 v = make_float4(0.f, 0.f, 0.f, 0.f);
      if (!NCHK || (col0 + r) < N) v = *(const float4*)(W + (long)(col0 + r) * Kd + k0 + kk);
      Ws[kk + 0][r] = v.x; Ws[kk + 1][r] = v.y; Ws[kk + 2][r] = v.z; Ws[kk + 3][r] = v.w;
    }
    __syncthreads();
#pragma unroll
    for (int k = 0; k < BK; ++k) {
      float a[TM], w[TN];
#pragma unroll
      for (int i = 0; i < TM; i += 4) *(float4*)(a + i) = *(const float4*)(&As[k][ty * TM + i]);
#pragma unroll
      for (int j = 0; j < TN; j += 4) *(float4*)(w + j) = *(const float4*)(&Ws[k][tx * TN + j]);
#pragma unroll
      for (int i = 0; i < TM; ++i)
#pragma unroll
        for (int j = 0; j < TN; ++j) acc[i][j] = fmaf(a[i], w[j], acc[i][j]);
    }
    __syncthreads();
  }
#pragma unroll
  for (int i = 0; i < TM; ++i) {
    int r = row0 + ty * TM + i;
#pragma unroll
    for (int j = 0; j < TN; ++j) {
      int c = col0 + tx * TN + j;
      if (NCHK && c >= N) continue;
      float v = acc[i][j];
      if (BIAS) v += bias[c];
      if (ACT == 1) v = fmaxf(v, 0.f) + log1pf(__expf(-fabsf(v)));  // softplus, stable
      float* p = C + (long)r * ldc + c;
      if (RES) *p += v; else *p = v;
    }
  }
}

__global__ __launch_bounds__(256) void rmsnorm_k(const float* __restrict__ h,
                                                 const float* __restrict__ w,
                                                 float* __restrict__ o) {
  const int t = blockIdx.x, d = threadIdx.x;
  float v = h[t * NDM + d];
  float s = v * v;
#pragma unroll
  for (int off = 32; off >= 1; off >>= 1) s += __shfl_xor(s, off);
  __shared__ float red[4];
  if ((d & 63) == 0) red[d >> 6] = s;
  __syncthreads();
  float tot = red[0] + red[1] + red[2] + red[3];
  o[t * NDM + d] = v * rsqrtf(tot * (1.f / NDM) + 1e-6f) * w[d];
}

// u2 = silu(depthwise causal conv(u)), u = xz[:, :512]
__global__ __launch_bounds__(256) void conv_silu_k(const float* __restrict__ xz,
                                                   const float* __restrict__ cw,
                                                   const float* __restrict__ cb,
                                                   float* __restrict__ u2) {
  const int t = blockIdx.x, l = t & (LSEQ - 1);
#pragma unroll
  for (int half = 0; half < 2; ++half) {
    const int c = threadIdx.x + half * 256;
    float acc = cb[c];
#pragma unroll
    for (int k = 0; k < 4; ++k) {
      int lp = l - 3 + k;
      if (lp >= 0) acc = fmaf(xz[(t - 3 + k) * 1024 + c], cw[c * 4 + k], acc);
    }
    u2[t * NDI + c] = acc * sigmoidf_(acc);
  }
}

// ---- chunked parallel selective scan ----
// Phase A: per-(b,chunk,d,n) local scan from 0; store end-state and prod(dA).
// Layout of sEnd/prodA/carry: [b][c][d][n] flat == global lane id.
__global__ __launch_bounds__(256) void scan_chunkA(const float* __restrict__ delta,
                                                   const float* __restrict__ u2,
                                                   const float* __restrict__ dbc,
                                                   const float* __restrict__ Alog,
                                                   float* __restrict__ sEnd,
                                                   float* __restrict__ prodA) {
  const int g = blockIdx.x * 256 + threadIdx.x;
  const int n = g & 15, d = (g >> 4) & (NDI - 1), c = (g >> 13) & (NCH - 1), b = g >> 17;
  const float Acoef = -__expf(Alog[d * NDS + n]);
  float s = 0.f, P = 1.f;
  int t = b * LSEQ + c * CHUNK;
#pragma unroll 2
  for (int j = 0; j < CHUNK; ++j, ++t) {
    float dl = delta[t * NDI + d];
    float ul = u2[t * NDI + d];
    float Bn = dbc[t * 48 + NDR + n];
    float dA = __expf(dl * Acoef);
    s = fmaf(dA, s, dl * ul * Bn);
    P *= dA;
  }
  sEnd[g] = s;
  prodA[g] = P;
}

// Phase B: per-(b,d,n) sequential combine over the 16 chunks -> carry-in states.
__global__ __launch_bounds__(256) void scan_chunkB(const float* __restrict__ sEnd,
                                                   const float* __restrict__ prodA,
                                                   float* __restrict__ carry) {
  const int g = blockIdx.x * 256 + threadIdx.x;   // (b, d, n)
  const int dn = g & (NDI * NDS - 1);
  const int b = g >> 13;
  float h = 0.f;
  const int base = b * NCH * NDI * NDS + dn;
#pragma unroll
  for (int c = 0; c < NCH; ++c) {
    const int idx = base + c * NDI * NDS;
    carry[idx] = h;
    h = fmaf(prodA[idx], h, sEnd[idx]);
  }
}

// Phase C: re-run each chunk from carry; fuse C-contraction, u*D, silu(z) gate.
__global__ __launch_bounds__(256) void scan_chunkC(const float* __restrict__ delta,
                                                   const float* __restrict__ u2,
                                                   const float* __restrict__ dbc,
                                                   const float* __restrict__ xz,
                                                   const float* __restrict__ Alog,
                                                   const float* __restrict__ Dp,
                                                   const float* __restrict__ carry,
                                                   float* __restrict__ y) {
  const int g = blockIdx.x * 256 + threadIdx.x;
  const int n = g & 15, d = (g >> 4) & (NDI - 1), c = (g >> 13) & (NCH - 1), b = g >> 17;
  const float Acoef = -__expf(Alog[d * NDS + n]);
  const float Dv = Dp[d];
  float s = carry[g];
  int t = b * LSEQ + c * CHUNK;
#pragma unroll 2
  for (int j = 0; j < CHUNK; ++j, ++t) {
    float dl = delta[t * NDI + d];
    float ul = u2[t * NDI + d];
    float Bn = dbc[t * 48 + NDR + n];
    float Cn = dbc[t * 48 + NDR + NDS + n];
    float dA = __expf(dl * Acoef);
    s = fmaf(dA, s, dl * ul * Bn);
    float p = s * Cn;
    p += __shfl_xor(p, 1); p += __shfl_xor(p, 2);
    p += __shfl_xor(p, 4); p += __shfl_xor(p, 8);
    if (n == 0) {
      float zl = xz[t * 1024 + NDI + d];
      y[t * NDI + d] = (p + ul * Dv) * zl * sigmoidf_(zl);
    }
  }
}

__global__ __launch_bounds__(256) void pool_k(const float* __restrict__ hn,
                                              float* __restrict__ pooled) {
  const int b = blockIdx.y, d = threadIdx.x;
  const int base = b * LSEQ + blockIdx.x * 128;
  float acc = 0.f;
  for (int j = 0; j < 128; ++j) acc += hn[(base + j) * NDM + d];
  atomicAdd(pooled + b * NDM + d, acc * (1.f / LSEQ));
}

__global__ __launch_bounds__(128) void bias_k(const float* __restrict__ pooled,
                                              const float* __restrict__ pw,
                                              const float* __restrict__ pb,
                                              float* __restrict__ bv) {
  const int b = blockIdx.x, f = threadIdx.x;
  float acc = pb[f];
  for (int dd = 0; dd < NDM; ++dd) acc = fmaf(pooled[b * NDM + dd], pw[f * NDM + dd], acc);
  bv[b * NF + f] = acc;
}

__global__ __launch_bounds__(256) void addout_k(const float* __restrict__ x,
                                                const float* __restrict__ bv,
                                                float* __restrict__ out) {
  const int i4 = blockIdx.x * 256 + threadIdx.x;  // 262144 float4 total
  const float4 xv = ((const float4*)x)[i4];
  const int trow = i4 >> 5;      // 32 float4 per 128-wide row
  const int b = trow >> 11;      // 2048 rows per batch
  const int f4 = i4 & 31;
  const float4 bb = ((const float4*)bv)[b * 32 + f4];
  float4 o;
  o.x = xv.x + bb.x; o.y = xv.y + bb.y; o.z = xv.z + bb.z; o.w = xv.w + bb.w;
  ((float4*)out)[i4] = o;
}

extern "C" void kernel_launch(void* const* d_in, const int* in_sizes, int n_in,
                              void* d_out, int out_size, void* d_ws, size_t ws_size,
                              hipStream_t stream) {
  const float* x       = (const float*)d_in[0];
  const float* embed_w = (const float*)d_in[1];
  const float* embed_b = (const float*)d_in[2];
  const float* in_w    = (const float*)d_in[3];
  const float* conv_w  = (const float*)d_in[4];
  const float* conv_b  = (const float*)d_in[5];
  const float* xproj_w = (const float*)d_in[6];
  const float* dt_w    = (const float*)d_in[7];
  const float* dt_b    = (const float*)d_in[8];
  const float* A_log   = (const float*)d_in[9];
  const float* Dw      = (const float*)d_in[10];
  const float* out_w   = (const float*)d_in[11];
  const float* norm_w  = (const float*)d_in[12];
  const float* fnorm_w = (const float*)d_in[13];
  const float* proj_w  = (const float*)d_in[14];
  const float* proj_b  = (const float*)d_in[15];

  // workspace layout (floats), total ~97.5 MB
  float* ws     = (float*)d_ws;
  float* h      = ws;                           // 8192*256
  float* hn     = h     + (long)TTOK * NDM;     // 8192*256 (2M floats)
  float* xz     = hn    + (long)TTOK * NDM;     // 8192*1024 (u | z)
  float* u2     = xz    + (long)TTOK * 1024;    // 8192*512
  float* dbc    = u2    + (long)TTOK * NDI;     // 8192*48  (dt | B | C)
  float* delta  = dbc   + (long)TTOK * 48;      // 8192*512
  float* yb     = delta + (long)TTOK * NDI;     // 8192*512
  float* pooled = yb    + (long)TTOK * NDI;     // 4*256
  float* bv     = pooled + BATCH * NDM;         // 4*128

  // Scan scratch aliases hn: hn is dead between the in-proj GEMM (its last
  // reader) and the next rmsnorm (its next writer). Needs 3*524288 = 1.57M
  // floats <= 2M floats available in hn.
  const int SCN = BATCH * NCH * NDI * NDS;      // 524288
  float* sEnd  = hn;
  float* prodA = hn + SCN;
  float* carry = hn + 2 * SCN;

  // h = x @ embed_w^T + embed_b
  gemm_tn<64, 64, 16, 0, true, false, false><<<dim3(NDM / 64, TTOK / 64), 256, 0, stream>>>(
      x, NF, embed_w, embed_b, h, NDM, NDM, NF);

  for (int i = 0; i < 2; ++i) {
    const float* inw = in_w    + (long)i * 2 * NDI * NDM;
    const float* cw  = conv_w  + (long)i * NDI * 4;
    const float* cb  = conv_b  + (long)i * NDI;
    const float* xpw = xproj_w + (long)i * 48 * NDI;
    const float* dtw = dt_w    + (long)i * NDI * NDR;
    const float* dtb = dt_b    + (long)i * NDI;
    const float* al  = A_log   + (long)i * NDI * NDS;
    const float* dd  = Dw      + (long)i * NDI;
    const float* ow  = out_w   + (long)i * NDM * NDI;

    rmsnorm_k<<<TTOK, 256, 0, stream>>>(h, norm_w + i * NDM, hn);
    // xz = hn @ in_w^T   (8192 x 1024 x 256)
    gemm_tn<128, 128, 16, 0, false, false, false><<<dim3(1024 / 128, TTOK / 128), 256, 0, stream>>>(
        hn, NDM, inw, nullptr, xz, 1024, 1024, NDM);
    conv_silu_k<<<TTOK, 256, 0, stream>>>(xz, cw, cb, u2);
    // dbc = u2 @ xproj_w^T  (8192 x 48 x 512)
    gemm_tn<64, 64, 16, 0, false, false, true><<<dim3(1, TTOK / 64), 256, 0, stream>>>(
        u2, NDI, xpw, nullptr, dbc, 48, 48, NDI);
    // delta = softplus(dt @ dt_w^T + dt_b)  (8192 x 512 x 16)
    gemm_tn<64, 64, 16, 1, true, false, false><<<dim3(NDI / 64, TTOK / 64), 256, 0, stream>>>(
        dbc, 48, dtw, dtb, delta, NDI, NDI, NDR);
    // chunked parallel scan (phases A/B/C)
    scan_chunkA<<<SCN / 256, 256, 0, stream>>>(delta, u2, dbc, al, sEnd, prodA);
    scan_chunkB<<<BATCH * NDI * NDS / 256, 256, 0, stream>>>(sEnd, prodA, carry);
    scan_chunkC<<<SCN / 256, 256, 0, stream>>>(delta, u2, dbc, xz, al, dd, carry, yb);
    // h += yb @ out_w^T   (8192 x 256 x 512)
    gemm_tn<64, 64, 16, 0, false, true, false><<<dim3(NDM / 64, TTOK / 64), 256, 0, stream>>>(
        yb, NDI, ow, nullptr, h, NDM, NDM, NDI);
  }

  rmsnorm_k<<<TTOK, 256, 0, stream>>>(h, fnorm_w, hn);
  hipMemsetAsync(pooled, 0, BATCH * NDM * sizeof(float), stream);
  pool_k<<<dim3(LSEQ / 128, BATCH), 256, 0, stream>>>(hn, pooled);
  bias_k<<<BATCH, 128, 0, stream>>>(pooled, proj_w, proj_b, bv);
  addout_k<<<TTOK * NF / 4 / 256, 256, 0, stream>>>(x, bv, (float*)d_out);
}

// Round 3
// 505.213 us; speedup vs baseline: 6.4775x; 1.3407x over previous
//
#include <hip/hip_runtime.h>

#define TTOK 8192   // B*L
#define BATCH 4
#define LSEQ 2048
#define NDM 256
#define NF 128
#define NDI 512
#define NDS 16
#define NDR 16
#define CHUNK 32
#define NCH (LSEQ / CHUNK)   // 64

__device__ __forceinline__ float sigmoidf_(float x) { return 1.f / (1.f + __expf(-x)); }

// C[m,n] = act(sum_k A[m,k]*W[n,k] + bias[n]) [+= if RES]
// A: (M, lda) row-major. W: (N, Kd) row-major. M must be multiple of BM.
template<int BM, int BN, int BK, int ACT, bool BIAS, bool RES, bool NCHK>
__global__ __launch_bounds__(256) void gemm_tn(const float* __restrict__ A, int lda,
                                               const float* __restrict__ W,
                                               const float* __restrict__ bias,
                                               float* __restrict__ C, int ldc,
                                               int N, int Kd) {
  constexpr int TM = BM / 16, TN = BN / 16;
  __shared__ float As[BK][BM + 4];
  __shared__ float Ws[BK][BN + 4];
  const int tid = threadIdx.x;
  const int tx = tid & 15, ty = tid >> 4;
  const int row0 = blockIdx.y * BM;
  const int col0 = blockIdx.x * BN;
  float acc[TM][TN] = {};
  for (int k0 = 0; k0 < Kd; k0 += BK) {
    for (int idx = tid; idx < BM * BK / 4; idx += 256) {
      int r = (idx << 2) / BK, kk = (idx << 2) % BK;
      float4 v = *(const float4*)(A + (long)(row0 + r) * lda + k0 + kk);
      As[kk + 0][r] = v.x; As[kk + 1][r] = v.y; As[kk + 2][r] = v.z; As[kk + 3][r] = v.w;
    }
    for (int idx = tid; idx < BN * BK / 4; idx += 256) {
      int r = (idx << 2) / BK, kk = (idx << 2) % BK;
      float4 v = make_float4(0.f, 0.f, 0.f, 0.f);
      if (!NCHK || (col0 + r) < N) v = *(const float4*)(W + (long)(col0 + r) * Kd + k0 + kk);
      Ws[kk + 0][r] = v.x; Ws[kk + 1][r] = v.y; Ws[kk + 2][r] = v.z; Ws[kk + 3][r] = v.w;
    }
    __syncthreads();
#pragma unroll
    for (int k = 0; k < BK; ++k) {
      float a[TM], w[TN];
#pragma unroll
      for (int i = 0; i < TM; i += 4) *(float4*)(a + i) = *(const float4*)(&As[k][ty * TM + i]);
#pragma unroll
      for (int j = 0; j < TN; j += 4) *(float4*)(w + j) = *(const float4*)(&Ws[k][tx * TN + j]);
#pragma unroll
      for (int i = 0; i < TM; ++i)
#pragma unroll
        for (int j = 0; j < TN; ++j) acc[i][j] = fmaf(a[i], w[j], acc[i][j]);
    }
    __syncthreads();
  }
#pragma unroll
  for (int i = 0; i < TM; ++i) {
    int r = row0 + ty * TM + i;
#pragma unroll
    for (int j = 0; j < TN; ++j) {
      int c = col0 + tx * TN + j;
      if (NCHK && c >= N) continue;
      float v = acc[i][j];
      if (BIAS) v += bias[c];
      if (ACT == 1) v = fmaxf(v, 0.f) + log1pf(__expf(-fabsf(v)));  // softplus, stable
      float* p = C + (long)r * ldc + c;
      if (RES) *p += v; else *p = v;
    }
  }
}

__global__ __launch_bounds__(256) void rmsnorm_k(const float* __restrict__ h,
                                                 const float* __restrict__ w,
                                                 float* __restrict__ o) {
  const int t = blockIdx.x, d = threadIdx.x;
  float v = h[t * NDM + d];
  float s = v * v;
#pragma unroll
  for (int off = 32; off >= 1; off >>= 1) s += __shfl_xor(s, off);
  __shared__ float red[4];
  if ((d & 63) == 0) red[d >> 6] = s;
  __syncthreads();
  float tot = red[0] + red[1] + red[2] + red[3];
  o[t * NDM + d] = v * rsqrtf(tot * (1.f / NDM) + 1e-6f) * w[d];
}

// u2 = silu(depthwise causal conv(u)), u = xz[:, :512]
__global__ __launch_bounds__(256) void conv_silu_k(const float* __restrict__ xz,
                                                   const float* __restrict__ cw,
                                                   const float* __restrict__ cb,
                                                   float* __restrict__ u2) {
  const int t = blockIdx.x, l = t & (LSEQ - 1);
#pragma unroll
  for (int half = 0; half < 2; ++half) {
    const int c = threadIdx.x + half * 256;
    float acc = cb[c];
#pragma unroll
    for (int k = 0; k < 4; ++k) {
      int lp = l - 3 + k;
      if (lp >= 0) acc = fmaf(xz[(t - 3 + k) * 1024 + c], cw[c * 4 + k], acc);
    }
    u2[t * NDI + c] = acc * sigmoidf_(acc);
  }
}

// ---- chunked parallel selective scan, thread-per-(b,c,d), 16 states in regs ----
// blockIdx decomposition keeps (b,c) block-uniform so B/C row loads scalarize.
// Scratch layout [b][c][d][n] flat; per-thread base = ((b*NCH+c)*NDI+d)*NDS.

__global__ __launch_bounds__(256) void scanA(const float* __restrict__ delta,
                                             const float* __restrict__ u2,
                                             const float* __restrict__ dbc,
                                             const float* __restrict__ Alog,
                                             float* __restrict__ sEnd,
                                             float* __restrict__ prodA) {
  const int d = ((blockIdx.x & 1) << 8) + threadIdx.x;
  const int cb = blockIdx.x >> 1;
  const int c = cb & (NCH - 1), b = cb >> 6;
  float Ac[16];
#pragma unroll
  for (int q = 0; q < 4; ++q) {
    float4 v = *(const float4*)(Alog + d * NDS + q * 4);
    Ac[q * 4 + 0] = -__expf(v.x); Ac[q * 4 + 1] = -__expf(v.y);
    Ac[q * 4 + 2] = -__expf(v.z); Ac[q * 4 + 3] = -__expf(v.w);
  }
  float s[16] = {};
  float P[16];
#pragma unroll
  for (int n = 0; n < 16; ++n) P[n] = 1.f;
  int t = b * LSEQ + c * CHUNK;
  for (int j = 0; j < CHUNK; ++j, ++t) {
    float dl = delta[t * NDI + d];
    float ul = u2[t * NDI + d];
    float du = dl * ul;
#pragma unroll
    for (int q = 0; q < 4; ++q) {
      float4 Bv = *(const float4*)(dbc + t * 48 + NDR + q * 4);
      float Be[4] = {Bv.x, Bv.y, Bv.z, Bv.w};
#pragma unroll
      for (int e = 0; e < 4; ++e) {
        int n = q * 4 + e;
        float dA = __expf(dl * Ac[n]);
        s[n] = fmaf(dA, s[n], du * Be[e]);
        P[n] *= dA;
      }
    }
  }
  const long base = ((long)((b * NCH + c) * NDI + d)) * NDS;
#pragma unroll
  for (int q = 0; q < 4; ++q) {
    *(float4*)(sEnd + base + q * 4) =
        make_float4(s[q * 4], s[q * 4 + 1], s[q * 4 + 2], s[q * 4 + 3]);
    *(float4*)(prodA + base + q * 4) =
        make_float4(P[q * 4], P[q * 4 + 1], P[q * 4 + 2], P[q * 4 + 3]);
  }
}

// Phase B: per-(b,d,n) sequential combine over the NCH chunks -> carry-in states.
__global__ __launch_bounds__(256) void scanB(const float* __restrict__ sEnd,
                                             const float* __restrict__ prodA,
                                             float* __restrict__ carry) {
  const int g = blockIdx.x * 256 + threadIdx.x;   // (b, d*16+n)
  const int dn = g & (NDI * NDS - 1);
  const int b = g >> 13;
  float h = 0.f;
  const long base = (long)b * NCH * NDI * NDS + dn;
#pragma unroll 4
  for (int c = 0; c < NCH; ++c) {
    const long idx = base + (long)c * NDI * NDS;
    carry[idx] = h;
    h = fmaf(prodA[idx], h, sEnd[idx]);
  }
}

// Phase C: re-run each chunk from carry; fused C-contraction, u*D, silu(z) gate.
__global__ __launch_bounds__(256) void scanC(const float* __restrict__ delta,
                                             const float* __restrict__ u2,
                                             const float* __restrict__ dbc,
                                             const float* __restrict__ xz,
                                             const float* __restrict__ Alog,
                                             const float* __restrict__ Dp,
                                             const float* __restrict__ carry,
                                             float* __restrict__ y) {
  const int d = ((blockIdx.x & 1) << 8) + threadIdx.x;
  const int cb = blockIdx.x >> 1;
  const int c = cb & (NCH - 1), b = cb >> 6;
  float Ac[16];
#pragma unroll
  for (int q = 0; q < 4; ++q) {
    float4 v = *(const float4*)(Alog + d * NDS + q * 4);
    Ac[q * 4 + 0] = -__expf(v.x); Ac[q * 4 + 1] = -__expf(v.y);
    Ac[q * 4 + 2] = -__expf(v.z); Ac[q * 4 + 3] = -__expf(v.w);
  }
  const float Dv = Dp[d];
  float s[16];
  const long base = ((long)((b * NCH + c) * NDI + d)) * NDS;
#pragma unroll
  for (int q = 0; q < 4; ++q) {
    float4 v = *(const float4*)(carry + base + q * 4);
    s[q * 4 + 0] = v.x; s[q * 4 + 1] = v.y; s[q * 4 + 2] = v.z; s[q * 4 + 3] = v.w;
  }
  int t = b * LSEQ + c * CHUNK;
  for (int j = 0; j < CHUNK; ++j, ++t) {
    float dl = delta[t * NDI + d];
    float ul = u2[t * NDI + d];
    float du = dl * ul;
    float p = 0.f;
#pragma unroll
    for (int q = 0; q < 4; ++q) {
      float4 Bv = *(const float4*)(dbc + t * 48 + NDR + q * 4);
      float4 Cv = *(const float4*)(dbc + t * 48 + NDR + NDS + q * 4);
      float Be[4] = {Bv.x, Bv.y, Bv.z, Bv.w};
      float Ce[4] = {Cv.x, Cv.y, Cv.z, Cv.w};
#pragma unroll
      for (int e = 0; e < 4; ++e) {
        int n = q * 4 + e;
        float dA = __expf(dl * Ac[n]);
        s[n] = fmaf(dA, s[n], du * Be[e]);
        p = fmaf(s[n], Ce[e], p);
      }
    }
    float zl = xz[t * 1024 + NDI + d];
    y[t * NDI + d] = (p + ul * Dv) * zl * sigmoidf_(zl);
  }
}

__global__ __launch_bounds__(256) void pool_k(const float* __restrict__ hn,
                                              float* __restrict__ pooled) {
  const int b = blockIdx.y, d = threadIdx.x;
  const int base = b * LSEQ + blockIdx.x * 128;
  float acc = 0.f;
  for (int j = 0; j < 128; ++j) acc += hn[(base + j) * NDM + d];
  atomicAdd(pooled + b * NDM + d, acc * (1.f / LSEQ));
}

__global__ __launch_bounds__(128) void bias_k(const float* __restrict__ pooled,
                                              const float* __restrict__ pw,
                                              const float* __restrict__ pb,
                                              float* __restrict__ bv) {
  const int b = blockIdx.x, f = threadIdx.x;
  float acc = pb[f];
  for (int dd = 0; dd < NDM; ++dd) acc = fmaf(pooled[b * NDM + dd], pw[f * NDM + dd], acc);
  bv[b * NF + f] = acc;
}

__global__ __launch_bounds__(256) void addout_k(const float* __restrict__ x,
                                                const float* __restrict__ bv,
                                                float* __restrict__ out) {
  const int i4 = blockIdx.x * 256 + threadIdx.x;  // 262144 float4 total
  const float4 xv = ((const float4*)x)[i4];
  const int trow = i4 >> 5;      // 32 float4 per 128-wide row
  const int b = trow >> 11;      // 2048 rows per batch
  const int f4 = i4 & 31;
  const float4 bb = ((const float4*)bv)[b * 32 + f4];
  float4 o;
  o.x = xv.x + bb.x; o.y = xv.y + bb.y; o.z = xv.z + bb.z; o.w = xv.w + bb.w;
  ((float4*)out)[i4] = o;
}

extern "C" void kernel_launch(void* const* d_in, const int* in_sizes, int n_in,
                              void* d_out, int out_size, void* d_ws, size_t ws_size,
                              hipStream_t stream) {
  const float* x       = (const float*)d_in[0];
  const float* embed_w = (const float*)d_in[1];
  const float* embed_b = (const float*)d_in[2];
  const float* in_w    = (const float*)d_in[3];
  const float* conv_w  = (const float*)d_in[4];
  const float* conv_b  = (const float*)d_in[5];
  const float* xproj_w = (const float*)d_in[6];
  const float* dt_w    = (const float*)d_in[7];
  const float* dt_b    = (const float*)d_in[8];
  const float* A_log   = (const float*)d_in[9];
  const float* Dw      = (const float*)d_in[10];
  const float* out_w   = (const float*)d_in[11];
  const float* norm_w  = (const float*)d_in[12];
  const float* fnorm_w = (const float*)d_in[13];
  const float* proj_w  = (const float*)d_in[14];
  const float* proj_b  = (const float*)d_in[15];

  // workspace layout (floats), total ~97.5 MB
  float* ws     = (float*)d_ws;
  float* h      = ws;                           // 8192*256
  float* hn     = h     + (long)TTOK * NDM;     // 8192*256 (2M floats)
  float* xz     = hn    + (long)TTOK * NDM;     // 8192*1024 (u | z)
  float* u2     = xz    + (long)TTOK * 1024;    // 8192*512
  float* dbc    = u2    + (long)TTOK * NDI;     // 8192*48  (dt | B | C)
  float* delta  = dbc   + (long)TTOK * 48;      // 8192*512
  float* yb     = delta + (long)TTOK * NDI;     // 8192*512 (4M floats)
  float* pooled = yb    + (long)TTOK * NDI;     // 4*256
  float* bv     = pooled + BATCH * NDM;         // 4*128

  // Scan scratch aliasing:
  //   sEnd/prodA (2M floats each) -> yb (4M floats; scanC overwrites yb with y
  //     AFTER phase B has consumed sEnd/prodA).
  //   carry (2M floats) -> hn (dead after the in-proj GEMM reads it).
  const long SCN = (long)BATCH * NCH * NDI * NDS;   // 2,097,152
  float* sEnd  = yb;
  float* prodA = yb + SCN;
  float* carry = hn;

  // h = x @ embed_w^T + embed_b
  gemm_tn<64, 64, 16, 0, true, false, false><<<dim3(NDM / 64, TTOK / 64), 256, 0, stream>>>(
      x, NF, embed_w, embed_b, h, NDM, NDM, NF);

  for (int i = 0; i < 2; ++i) {
    const float* inw = in_w    + (long)i * 2 * NDI * NDM;
    const float* cw  = conv_w  + (long)i * NDI * 4;
    const float* cb  = conv_b  + (long)i * NDI;
    const float* xpw = xproj_w + (long)i * 48 * NDI;
    const float* dtw = dt_w    + (long)i * NDI * NDR;
    const float* dtb = dt_b    + (long)i * NDI;
    const float* al  = A_log   + (long)i * NDI * NDS;
    const float* dd  = Dw      + (long)i * NDI;
    const float* ow  = out_w   + (long)i * NDM * NDI;

    rmsnorm_k<<<TTOK, 256, 0, stream>>>(h, norm_w + i * NDM, hn);
    // xz = hn @ in_w^T   (8192 x 1024 x 256)
    gemm_tn<128, 128, 16, 0, false, false, false><<<dim3(1024 / 128, TTOK / 128), 256, 0, stream>>>(
        hn, NDM, inw, nullptr, xz, 1024, 1024, NDM);
    conv_silu_k<<<TTOK, 256, 0, stream>>>(xz, cw, cb, u2);
    // dbc = u2 @ xproj_w^T  (8192 x 48 x 512)
    gemm_tn<64, 64, 16, 0, false, false, true><<<dim3(1, TTOK / 64), 256, 0, stream>>>(
        u2, NDI, xpw, nullptr, dbc, 48, 48, NDI);
    // delta = softplus(dt @ dt_w^T + dt_b)  (8192 x 512 x 16)
    gemm_tn<64, 64, 16, 1, true, false, false><<<dim3(NDI / 64, TTOK / 64), 256, 0, stream>>>(
        dbc, 48, dtw, dtb, delta, NDI, NDI, NDR);
    // chunked parallel scan (phases A/B/C)
    scanA<<<BATCH * NCH * 2, 256, 0, stream>>>(delta, u2, dbc, al, sEnd, prodA);
    scanB<<<BATCH * NDI * NDS / 256, 256, 0, stream>>>(sEnd, prodA, carry);
    scanC<<<BATCH * NCH * 2, 256, 0, stream>>>(delta, u2, dbc, xz, al, dd, carry, yb);
    // h += yb @ out_w^T   (8192 x 256 x 512)
    gemm_tn<64, 64, 16, 0, false, true, false><<<dim3(NDM / 64, TTOK / 64), 256, 0, stream>>>(
        yb, NDI, ow, nullptr, h, NDM, NDM, NDI);
  }

  rmsnorm_k<<<TTOK, 256, 0, stream>>>(h, fnorm_w, hn);
  hipMemsetAsync(pooled, 0, BATCH * NDM * sizeof(float), stream);
  pool_k<<<dim3(LSEQ / 128, BATCH), 256, 0, stream>>>(hn, pooled);
  bias_k<<<BATCH, 128, 0, stream>>>(pooled, proj_w, proj_b, bv);
  addout_k<<<TTOK * NF / 4 / 256, 256, 0, stream>>>(x, bv, (float*)d_out);
}

// Round 4
// 366.628 us; speedup vs baseline: 8.9259x; 1.3780x over previous
//
#include <hip/hip_runtime.h>

#define TTOK 8192   // B*L
#define BATCH 4
#define LSEQ 2048
#define NDM 256
#define NF 128
#define NDI 512
#define NDS 16
#define NDR 16
#define CHUNK 32
#define NCH (LSEQ / CHUNK)   // 64

typedef unsigned short u16;
typedef __attribute__((ext_vector_type(8))) short bf16x8;
typedef __attribute__((ext_vector_type(4))) float f32x4;

__device__ __forceinline__ float sigmoidf_(float x) { return 1.f / (1.f + __expf(-x)); }

__device__ __forceinline__ u16 f2bf(float f) {  // RTN-even
  unsigned u = __float_as_uint(f);
  u += 0x7FFF + ((u >> 16) & 1);
  return (u16)(u >> 16);
}

// ---------------- bf16 MFMA GEMM ----------------
// C[m,n] (f32) = A[m,:]·W[n,:] (+bias) (+= if RES). A:[M][K] bf16, W:[N][K] bf16.
// Tile 128 x BN_T, BK=64, 4 waves (2x2), per-wave 64 x BN_T/2.
// LDS: rows 0..127 = A-tile, rows 128..128+BN_T-1 = W-tile, 64 bf16 (128B) per row.
// XOR swizzle: 16B-chunk ck of row r lives at linear chunk ck^(r&7); staging
// keeps LDS writes linear (global_load_lds) and pre-swizzles the GLOBAL source
// chunk; ds_read applies the same XOR -> 2-way banks (free).
template<int BN_T, bool BIAS, bool RES>
__global__ __launch_bounds__(256) void gemm_bf16(const u16* __restrict__ A,
                                                 const u16* __restrict__ W,
                                                 const float* __restrict__ bias,
                                                 float* __restrict__ C,
                                                 int N, int K) {
  constexpr int NR = BN_T / 32;          // 16-col frags per wave
  constexpr int ROWS = 128 + BN_T;
  constexpr int CPW = (ROWS / 8) / 4;    // 1KB staging chunks per wave
  __shared__ u16 lds[ROWS * 64];
  const int tid = threadIdx.x;
  const int wave = tid >> 6, lane = tid & 63;
  const int wrow = wave >> 1, wcol = wave & 1;
  const int lr = lane & 15, lg = lane >> 4;
  const int row0 = blockIdx.y * 128, col0 = blockIdx.x * BN_T;

  // staging precompute: chunk q = wave*CPW+i covers LDS bytes [q*1024,(q+1)*1024)
  const u16* srcp[CPW];
  u16* ldsp[CPW];
#pragma unroll
  for (int i = 0; i < CPW; ++i) {
    const int q = wave * CPW + i;
    const int row = q * 8 + (lane >> 3);       // LDS row (128B each)
    const int ck = lane & 7;                   // linear 16B chunk in row
    const int sck = ck ^ (row & 7);            // swizzled source chunk
    const long grow = (row < 128) ? ((long)(row0 + row) * K)
                                  : ((long)(col0 + row - 128) * K);
    srcp[i] = ((row < 128) ? A : W) + grow + sck * 8;
    ldsp[i] = (u16*)&lds[q * 512];
  }

  // fragment read offsets
  int aoff[4], as7[4], boff[NR], bs7[NR];
#pragma unroll
  for (int m = 0; m < 4; ++m) {
    const int r = wrow * 64 + m * 16 + lr;
    aoff[m] = r * 64; as7[m] = r & 7;
  }
#pragma unroll
  for (int n = 0; n < NR; ++n) {
    const int r = 128 + wcol * (BN_T / 2) + n * 16 + lr;
    boff[n] = r * 64; bs7[n] = r & 7;
  }

  f32x4 acc[4][NR];
#pragma unroll
  for (int m = 0; m < 4; ++m)
#pragma unroll
    for (int n = 0; n < NR; ++n) acc[m][n] = (f32x4)(0.f);

  for (int k0 = 0; k0 < K; k0 += 64) {
#pragma unroll
    for (int i = 0; i < CPW; ++i)
      __builtin_amdgcn_global_load_lds(
          (const __attribute__((address_space(1))) unsigned int*)(srcp[i] + k0),
          (__attribute__((address_space(3))) unsigned int*)(ldsp[i]), 16, 0, 0);
    __syncthreads();   // drains vmcnt+lgkmcnt: tile resident

    bf16x8 af[2][4], bfr[2][NR];
#pragma unroll
    for (int kq = 0; kq < 2; ++kq) {
      const int kc = kq * 4 + lg;
#pragma unroll
      for (int m = 0; m < 4; ++m)
        af[kq][m] = *(const bf16x8*)(lds + aoff[m] + ((kc ^ as7[m]) << 3));
#pragma unroll
      for (int n = 0; n < NR; ++n)
        bfr[kq][n] = *(const bf16x8*)(lds + boff[n] + ((kc ^ bs7[n]) << 3));
    }
#pragma unroll
    for (int kq = 0; kq < 2; ++kq)
#pragma unroll
      for (int m = 0; m < 4; ++m)
#pragma unroll
        for (int n = 0; n < NR; ++n)
          acc[m][n] = __builtin_amdgcn_mfma_f32_16x16x32_bf16(af[kq][m], bfr[kq][n],
                                                              acc[m][n], 0, 0, 0);
    __syncthreads();   // all waves done reading before next overwrite
  }

  // C/D layout (verified m89/m91): col = lane&15, row = (lane>>4)*4 + j
#pragma unroll
  for (int m = 0; m < 4; ++m) {
    const int r0 = row0 + wrow * 64 + m * 16 + lg * 4;
#pragma unroll
    for (int n = 0; n < NR; ++n) {
      const int c = col0 + wcol * (BN_T / 2) + n * 16 + lr;
      const float bv = BIAS ? bias[c] : 0.f;
#pragma unroll
      for (int j = 0; j < 4; ++j) {
        float v = acc[m][n][j] + bv;
        float* p = C + (long)(r0 + j) * N + c;
        if (RES) *p += v; else *p = v;
      }
    }
  }
}

// f32 -> bf16 conversion, 4 elems/thread; total elems must be multiple of 1024
__global__ __launch_bounds__(256) void cvt4_k(const float* __restrict__ s,
                                              u16* __restrict__ d) {
  const int i = blockIdx.x * 256 + threadIdx.x;
  const float4 v = ((const float4*)s)[i];
  ushort4 o;
  o.x = f2bf(v.x); o.y = f2bf(v.y); o.z = f2bf(v.z); o.w = f2bf(v.w);
  ((ushort4*)d)[i] = o;
}

// ---------------- f32 tiled GEMM (small shapes) ----------------
template<int BM, int BN, int BK, int ACT, bool BIAS, bool RES, bool NCHK>
__global__ __launch_bounds__(256) void gemm_tn(const float* __restrict__ A, int lda,
                                               const float* __restrict__ W,
                                               const float* __restrict__ bias,
                                               float* __restrict__ C, int ldc,
                                               int N, int Kd) {
  constexpr int TM = BM / 16, TN = BN / 16;
  __shared__ float As[BK][BM + 4];
  __shared__ float Ws[BK][BN + 4];
  const int tid = threadIdx.x;
  const int tx = tid & 15, ty = tid >> 4;
  const int row0 = blockIdx.y * BM;
  const int col0 = blockIdx.x * BN;
  float acc[TM][TN] = {};
  for (int k0 = 0; k0 < Kd; k0 += BK) {
    for (int idx = tid; idx < BM * BK / 4; idx += 256) {
      int r = (idx << 2) / BK, kk = (idx << 2) % BK;
      float4 v = *(const float4*)(A + (long)(row0 + r) * lda + k0 + kk);
      As[kk + 0][r] = v.x; As[kk + 1][r] = v.y; As[kk + 2][r] = v.z; As[kk + 3][r] = v.w;
    }
    for (int idx = tid; idx < BN * BK / 4; idx += 256) {
      int r = (idx << 2) / BK, kk = (idx << 2) % BK;
      float4 v = make_float4(0.f, 0.f, 0.f, 0.f);
      if (!NCHK || (col0 + r) < N) v = *(const float4*)(W + (long)(col0 + r) * Kd + k0 + kk);
      Ws[kk + 0][r] = v.x; Ws[kk + 1][r] = v.y; Ws[kk + 2][r] = v.z; Ws[kk + 3][r] = v.w;
    }
    __syncthreads();
#pragma unroll
    for (int k = 0; k < BK; ++k) {
      float a[TM], w[TN];
#pragma unroll
      for (int i = 0; i < TM; i += 4) *(float4*)(a + i) = *(const float4*)(&As[k][ty * TM + i]);
#pragma unroll
      for (int j = 0; j < TN; j += 4) *(float4*)(w + j) = *(const float4*)(&Ws[k][tx * TN + j]);
#pragma unroll
      for (int i = 0; i < TM; ++i)
#pragma unroll
        for (int j = 0; j < TN; ++j) acc[i][j] = fmaf(a[i], w[j], acc[i][j]);
    }
    __syncthreads();
  }
#pragma unroll
  for (int i = 0; i < TM; ++i) {
    int r = row0 + ty * TM + i;
#pragma unroll
    for (int j = 0; j < TN; ++j) {
      int c = col0 + tx * TN + j;
      if (NCHK && c >= N) continue;
      float v = acc[i][j];
      if (BIAS) v += bias[c];
      if (ACT == 1) v = fmaxf(v, 0.f) + log1pf(__expf(-fabsf(v)));  // softplus
      float* p = C + (long)r * ldc + c;
      if (RES) *p += v; else *p = v;
    }
  }
}

// rmsnorm; OBF: write bf16 (feeds MFMA GEMM) else f32
template<bool OBF>
__global__ __launch_bounds__(256) void rmsnorm_k(const float* __restrict__ h,
                                                 const float* __restrict__ w,
                                                 void* __restrict__ o) {
  const int t = blockIdx.x, d = threadIdx.x;
  float v = h[t * NDM + d];
  float s = v * v;
#pragma unroll
  for (int off = 32; off >= 1; off >>= 1) s += __shfl_xor(s, off);
  __shared__ float red[4];
  if ((d & 63) == 0) red[d >> 6] = s;
  __syncthreads();
  float tot = red[0] + red[1] + red[2] + red[3];
  float r = v * rsqrtf(tot * (1.f / NDM) + 1e-6f) * w[d];
  if (OBF) ((u16*)o)[t * NDM + d] = f2bf(r);
  else     ((float*)o)[t * NDM + d] = r;
}

// u2 = silu(depthwise causal conv(u)), u = xz[:, :512]
__global__ __launch_bounds__(256) void conv_silu_k(const float* __restrict__ xz,
                                                   const float* __restrict__ cw,
                                                   const float* __restrict__ cb,
                                                   float* __restrict__ u2) {
  const int t = blockIdx.x, l = t & (LSEQ - 1);
#pragma unroll
  for (int half = 0; half < 2; ++half) {
    const int c = threadIdx.x + half * 256;
    float acc = cb[c];
#pragma unroll
    for (int k = 0; k < 4; ++k) {
      int lp = l - 3 + k;
      if (lp >= 0) acc = fmaf(xz[(t - 3 + k) * 1024 + c], cw[c * 4 + k], acc);
    }
    u2[t * NDI + c] = acc * sigmoidf_(acc);
  }
}

// ---- chunked parallel selective scan, thread-per-(b,c,d), 16 states in regs ----
__global__ __launch_bounds__(256) void scanA(const float* __restrict__ delta,
                                             const float* __restrict__ u2,
                                             const float* __restrict__ dbc,
                                             const float* __restrict__ Alog,
                                             float* __restrict__ sEnd,
                                             float* __restrict__ prodA) {
  const int d = ((blockIdx.x & 1) << 8) + threadIdx.x;
  const int cb = blockIdx.x >> 1;
  const int c = cb & (NCH - 1), b = cb >> 6;
  float Ac[16];
#pragma unroll
  for (int q = 0; q < 4; ++q) {
    float4 v = *(const float4*)(Alog + d * NDS + q * 4);
    Ac[q * 4 + 0] = -__expf(v.x); Ac[q * 4 + 1] = -__expf(v.y);
    Ac[q * 4 + 2] = -__expf(v.z); Ac[q * 4 + 3] = -__expf(v.w);
  }
  float s[16] = {};
  float P[16];
#pragma unroll
  for (int n = 0; n < 16; ++n) P[n] = 1.f;
  int t = b * LSEQ + c * CHUNK;
  for (int j = 0; j < CHUNK; ++j, ++t) {
    float dl = delta[t * NDI + d];
    float ul = u2[t * NDI + d];
    float du = dl * ul;
#pragma unroll
    for (int q = 0; q < 4; ++q) {
      float4 Bv = *(const float4*)(dbc + t * 48 + NDR + q * 4);
      float Be[4] = {Bv.x, Bv.y, Bv.z, Bv.w};
#pragma unroll
      for (int e = 0; e < 4; ++e) {
        int n = q * 4 + e;
        float dA = __expf(dl * Ac[n]);
        s[n] = fmaf(dA, s[n], du * Be[e]);
        P[n] *= dA;
      }
    }
  }
  const long base = ((long)((b * NCH + c) * NDI + d)) * NDS;
#pragma unroll
  for (int q = 0; q < 4; ++q) {
    *(float4*)(sEnd + base + q * 4) =
        make_float4(s[q * 4], s[q * 4 + 1], s[q * 4 + 2], s[q * 4 + 3]);
    *(float4*)(prodA + base + q * 4) =
        make_float4(P[q * 4], P[q * 4 + 1], P[q * 4 + 2], P[q * 4 + 3]);
  }
}

__global__ __launch_bounds__(256) void scanB(const float* __restrict__ sEnd,
                                             const float* __restrict__ prodA,
                                             float* __restrict__ carry) {
  const int g = blockIdx.x * 256 + threadIdx.x;   // (b, d*16+n)
  const int dn = g & (NDI * NDS - 1);
  const int b = g >> 13;
  float h = 0.f;
  const long base = (long)b * NCH * NDI * NDS + dn;
#pragma unroll 4
  for (int c = 0; c < NCH; ++c) {
    const long idx = base + (long)c * NDI * NDS;
    carry[idx] = h;
    h = fmaf(prodA[idx], h, sEnd[idx]);
  }
}

// Phase C: re-run chunk from carry; fused C-contraction, u*D, silu(z); bf16 out.
__global__ __launch_bounds__(256) void scanC(const float* __restrict__ delta,
                                             const float* __restrict__ u2,
                                             const float* __restrict__ dbc,
                                             const float* __restrict__ xz,
                                             const float* __restrict__ Alog,
                                             const float* __restrict__ Dp,
                                             const float* __restrict__ carry,
                                             u16* __restrict__ y) {
  const int d = ((blockIdx.x & 1) << 8) + threadIdx.x;
  const int cb = blockIdx.x >> 1;
  const int c = cb & (NCH - 1), b = cb >> 6;
  float Ac[16];
#pragma unroll
  for (int q = 0; q < 4; ++q) {
    float4 v = *(const float4*)(Alog + d * NDS + q * 4);
    Ac[q * 4 + 0] = -__expf(v.x); Ac[q * 4 + 1] = -__expf(v.y);
    Ac[q * 4 + 2] = -__expf(v.z); Ac[q * 4 + 3] = -__expf(v.w);
  }
  const float Dv = Dp[d];
  float s[16];
  const long base = ((long)((b * NCH + c) * NDI + d)) * NDS;
#pragma unroll
  for (int q = 0; q < 4; ++q) {
    float4 v = *(const float4*)(carry + base + q * 4);
    s[q * 4 + 0] = v.x; s[q * 4 + 1] = v.y; s[q * 4 + 2] = v.z; s[q * 4 + 3] = v.w;
  }
  int t = b * LSEQ + c * CHUNK;
  for (int j = 0; j < CHUNK; ++j, ++t) {
    float dl = delta[t * NDI + d];
    float ul = u2[t * NDI + d];
    float du = dl * ul;
    float p = 0.f;
#pragma unroll
    for (int q = 0; q < 4; ++q) {
      float4 Bv = *(const float4*)(dbc + t * 48 + NDR + q * 4);
      float4 Cv = *(const float4*)(dbc + t * 48 + NDR + NDS + q * 4);
      float Be[4] = {Bv.x, Bv.y, Bv.z, Bv.w};
      float Ce[4] = {Cv.x, Cv.y, Cv.z, Cv.w};
#pragma unroll
      for (int e = 0; e < 4; ++e) {
        int n = q * 4 + e;
        float dA = __expf(dl * Ac[n]);
        s[n] = fmaf(dA, s[n], du * Be[e]);
        p = fmaf(s[n], Ce[e], p);
      }
    }
    float zl = xz[t * 1024 + NDI + d];
    y[t * NDI + d] = f2bf((p + ul * Dv) * zl * sigmoidf_(zl));
  }
}

__global__ __launch_bounds__(256) void pool_k(const float* __restrict__ hn,
                                              float* __restrict__ pooled) {
  const int b = blockIdx.y, d = threadIdx.x;
  const int base = b * LSEQ + blockIdx.x * 128;
  float acc = 0.f;
  for (int j = 0; j < 128; ++j) acc += hn[(base + j) * NDM + d];
  atomicAdd(pooled + b * NDM + d, acc * (1.f / LSEQ));
}

__global__ __launch_bounds__(128) void bias_k(const float* __restrict__ pooled,
                                              const float* __restrict__ pw,
                                              const float* __restrict__ pb,
                                              float* __restrict__ bv) {
  const int b = blockIdx.x, f = threadIdx.x;
  float acc = pb[f];
  for (int dd = 0; dd < NDM; ++dd) acc = fmaf(pooled[b * NDM + dd], pw[f * NDM + dd], acc);
  bv[b * NF + f] = acc;
}

__global__ __launch_bounds__(256) void addout_k(const float* __restrict__ x,
                                                const float* __restrict__ bv,
                                                float* __restrict__ out) {
  const int i4 = blockIdx.x * 256 + threadIdx.x;
  const float4 xv = ((const float4*)x)[i4];
  const int trow = i4 >> 5;
  const int b = trow >> 11;
  const int f4 = i4 & 31;
  const float4 bb = ((const float4*)bv)[b * 32 + f4];
  float4 o;
  o.x = xv.x + bb.x; o.y = xv.y + bb.y; o.z = xv.z + bb.z; o.w = xv.w + bb.w;
  ((float4*)out)[i4] = o;
}

extern "C" void kernel_launch(void* const* d_in, const int* in_sizes, int n_in,
                              void* d_out, int out_size, void* d_ws, size_t ws_size,
                              hipStream_t stream) {
  const float* x       = (const float*)d_in[0];
  const float* embed_w = (const float*)d_in[1];
  const float* embed_b = (const float*)d_in[2];
  const float* in_w    = (const float*)d_in[3];
  const float* conv_w  = (const float*)d_in[4];
  const float* conv_b  = (const float*)d_in[5];
  const float* xproj_w = (const float*)d_in[6];
  const float* dt_w    = (const float*)d_in[7];
  const float* dt_b    = (const float*)d_in[8];
  const float* A_log   = (const float*)d_in[9];
  const float* Dw      = (const float*)d_in[10];
  const float* out_w   = (const float*)d_in[11];
  const float* norm_w  = (const float*)d_in[12];
  const float* fnorm_w = (const float*)d_in[13];
  const float* proj_w  = (const float*)d_in[14];
  const float* proj_b  = (const float*)d_in[15];

  // workspace layout (floats), ~97.6 MB — unchanged footprint
  float* ws     = (float*)d_ws;
  float* h      = ws;                           // 2M floats
  float* hn     = h     + (long)TTOK * NDM;     // 2M floats
  float* xz     = hn    + (long)TTOK * NDM;     // 8M floats (u | z)
  float* u2     = xz    + (long)TTOK * 1024;    // 4M floats
  float* dbc    = u2    + (long)TTOK * NDI;     // 0.375M floats (dt | B | C)
  float* delta  = dbc   + (long)TTOK * 48;      // 4M floats
  float* yb     = delta + (long)TTOK * NDI;     // 4M floats
  float* pooled = yb    + (long)TTOK * NDI;     // 4*256
  float* bv     = pooled + BATCH * NDM;         // 4*128

  // Time-multiplexed aliases (all verified against producer/consumer order):
  //   sEnd/prodA -> yb[0,2M)/[2M,4M)    (dead after scanB)
  //   ybb (bf16 scan out) -> yb[0,1M)   (written by scanC after scanB)
  //   carry -> hn[0,2M)                 (hnb dead after in-proj GEMM)
  //   hnb (bf16 rmsnorm out) -> hn[0,1M)
  //   xb (bf16 x) -> delta region       (dead once embed GEMM done)
  //   ewb -> u2 region                  (dead until conv_silu)
  //   inwb -> dbc region                (clobbered later by xproj output - OK)
  //   owb -> xz region                  (xz dead after scanC reads z)
  const long SCN = (long)BATCH * NCH * NDI * NDS;   // 2,097,152
  float* sEnd  = yb;
  float* prodA = yb + SCN;
  float* carry = hn;
  u16* ybb  = (u16*)yb;
  u16* hnb  = (u16*)hn;
  u16* xb   = (u16*)delta;
  u16* ewb  = (u16*)u2;
  u16* inwb = (u16*)dbc;
  u16* owb  = (u16*)xz;

  // x -> bf16 (1M elems), embed_w -> bf16 (32K elems)
  cvt4_k<<<TTOK * NF / 1024, 256, 0, stream>>>(x, xb);
  cvt4_k<<<NDM * NF / 1024, 256, 0, stream>>>(embed_w, ewb);
  // h = x @ embed_w^T + embed_b   (MFMA, 8192x256x128)
  gemm_bf16<64, true, false><<<dim3(NDM / 64, TTOK / 128), 256, 0, stream>>>(
      xb, ewb, embed_b, h, NDM, NF);

  for (int i = 0; i < 2; ++i) {
    const float* inw = in_w    + (long)i * 2 * NDI * NDM;
    const float* cw  = conv_w  + (long)i * NDI * 4;
    const float* cb  = conv_b  + (long)i * NDI;
    const float* xpw = xproj_w + (long)i * 48 * NDI;
    const float* dtw = dt_w    + (long)i * NDI * NDR;
    const float* dtb = dt_b    + (long)i * NDI;
    const float* al  = A_log   + (long)i * NDI * NDS;
    const float* dd  = Dw      + (long)i * NDI;
    const float* ow  = out_w   + (long)i * NDM * NDI;

    cvt4_k<<<2 * NDI * NDM / 1024, 256, 0, stream>>>(inw, inwb);
    rmsnorm_k<true><<<TTOK, 256, 0, stream>>>(h, norm_w + i * NDM, hnb);
    // xz = hn @ in_w^T   (MFMA, 8192x1024x256)
    gemm_bf16<128, false, false><<<dim3(1024 / 128, TTOK / 128), 256, 0, stream>>>(
        hnb, inwb, nullptr, xz, 1024, NDM);
    conv_silu_k<<<TTOK, 256, 0, stream>>>(xz, cw, cb, u2);
    // dbc = u2 @ xproj_w^T  (f32, 8192x48x512)
    gemm_tn<64, 64, 16, 0, false, false, true><<<dim3(1, TTOK / 64), 256, 0, stream>>>(
        u2, NDI, xpw, nullptr, dbc, 48, 48, NDI);
    // delta = softplus(dt @ dt_w^T + dt_b)  (f32, 8192x512x16)
    gemm_tn<64, 64, 16, 1, true, false, false><<<dim3(NDI / 64, TTOK / 64), 256, 0, stream>>>(
        dbc, 48, dtw, dtb, delta, NDI, NDI, NDR);
    // chunked parallel scan
    scanA<<<BATCH * NCH * 2, 256, 0, stream>>>(delta, u2, dbc, al, sEnd, prodA);
    scanB<<<BATCH * NDI * NDS / 256, 256, 0, stream>>>(sEnd, prodA, carry);
    scanC<<<BATCH * NCH * 2, 256, 0, stream>>>(delta, u2, dbc, xz, al, dd, carry, ybb);
    // h += yb @ out_w^T  (MFMA, 8192x256x512)
    cvt4_k<<<NDM * NDI / 1024, 256, 0, stream>>>(ow, owb);
    gemm_bf16<64, false, true><<<dim3(NDM / 64, TTOK / 128), 256, 0, stream>>>(
        ybb, owb, nullptr, h, NDM, NDI);
  }

  rmsnorm_k<false><<<TTOK, 256, 0, stream>>>(h, fnorm_w, hn);
  hipMemsetAsync(pooled, 0, BATCH * NDM * sizeof(float), stream);
  pool_k<<<dim3(LSEQ / 128, BATCH), 256, 0, stream>>>(hn, pooled);
  bias_k<<<BATCH, 128, 0, stream>>>(pooled, proj_w, proj_b, bv);
  addout_k<<<TTOK * NF / 4 / 256, 256, 0, stream>>>(x, bv, (float*)d_out);
}

// Round 6
// 341.611 us; speedup vs baseline: 9.5796x; 1.0732x over previous
//
#include <hip/hip_runtime.h>

#define TTOK 8192   // B*L
#define BATCH 4
#define LSEQ 2048
#define NDM 256
#define NF 128
#define NDI 512
#define NDS 16
#define NDR 16
#define CHUNK 32
#define NCH (LSEQ / CHUNK)   // 64

typedef unsigned short u16;
typedef __attribute__((ext_vector_type(8))) short bf16x8;
typedef __attribute__((ext_vector_type(4))) float f32x4;

__device__ __forceinline__ float sigmoidf_(float x) { return 1.f / (1.f + __expf(-x)); }

__device__ __forceinline__ u16 f2bf(float f) {  // RTN-even
  unsigned u = __float_as_uint(f);
  u += 0x7FFF + ((u >> 16) & 1);
  return (u16)(u >> 16);
}
__device__ __forceinline__ float bf2f(u16 v) {
  return __uint_as_float((unsigned)v << 16);
}
__device__ __forceinline__ float softplus_(float x) {  // stable
  return fmaxf(x, 0.f) + __logf(1.f + __expf(-fabsf(x)));
}

// ---------------- bf16 MFMA GEMM ----------------
// C[m,n] = A[m,:]·W[n,:] (+bias) (+= if RES). A:[M][K] bf16, W:[N][K] bf16.
// Tile 128 x BN_T, BK=64, 4 waves (2x2). OBF: C is bf16. NCHK: clamp W rows,
// skip C cols >= N. LDS rows: 0..127 A-tile, 128.. W-tile; 64 bf16/row.
// XOR swizzle on 16B chunks (pre-swizzled global source, swizzled ds_read).
template<int BN_T, bool BIAS, bool RES, bool OBF, bool NCHK>
__global__ __launch_bounds__(256) void gemm_bf16(const u16* __restrict__ A,
                                                 const u16* __restrict__ W,
                                                 const float* __restrict__ bias,
                                                 void* __restrict__ Cv,
                                                 int N, int K) {
  constexpr int NR = BN_T / 32;
  constexpr int ROWS = 128 + BN_T;
  constexpr int CPW = (ROWS / 8) / 4;
  __shared__ u16 lds[ROWS * 64];
  const int tid = threadIdx.x;
  const int wave = tid >> 6, lane = tid & 63;
  const int wrow = wave >> 1, wcol = wave & 1;
  const int lr = lane & 15, lg = lane >> 4;
  const int row0 = blockIdx.y * 128, col0 = blockIdx.x * BN_T;

  const u16* srcp[CPW];
  u16* ldsp[CPW];
#pragma unroll
  for (int i = 0; i < CPW; ++i) {
    const int q = wave * CPW + i;
    const int row = q * 8 + (lane >> 3);
    const int ck = lane & 7;
    const int sck = ck ^ (row & 7);
    long grow;
    if (row < 128) grow = (long)(row0 + row) * K;
    else {
      int wr = row - 128;
      if (NCHK && wr >= N) wr = N - 1;
      grow = (long)(col0 + wr) * K;
    }
    srcp[i] = ((row < 128) ? A : W) + grow + sck * 8;
    ldsp[i] = (u16*)&lds[q * 512];
  }

  int aoff[4], as7[4], boff[NR], bs7[NR];
#pragma unroll
  for (int m = 0; m < 4; ++m) {
    const int r = wrow * 64 + m * 16 + lr;
    aoff[m] = r * 64; as7[m] = r & 7;
  }
#pragma unroll
  for (int n = 0; n < NR; ++n) {
    const int r = 128 + wcol * (BN_T / 2) + n * 16 + lr;
    boff[n] = r * 64; bs7[n] = r & 7;
  }

  f32x4 acc[4][NR];
#pragma unroll
  for (int m = 0; m < 4; ++m)
#pragma unroll
    for (int n = 0; n < NR; ++n) acc[m][n] = (f32x4)(0.f);

  for (int k0 = 0; k0 < K; k0 += 64) {
#pragma unroll
    for (int i = 0; i < CPW; ++i)
      __builtin_amdgcn_global_load_lds(
          (const __attribute__((address_space(1))) unsigned int*)(srcp[i] + k0),
          (__attribute__((address_space(3))) unsigned int*)(ldsp[i]), 16, 0, 0);
    __syncthreads();

    bf16x8 af[2][4], bfr[2][NR];
#pragma unroll
    for (int kq = 0; kq < 2; ++kq) {
      const int kc = kq * 4 + lg;
#pragma unroll
      for (int m = 0; m < 4; ++m)
        af[kq][m] = *(const bf16x8*)(lds + aoff[m] + ((kc ^ as7[m]) << 3));
#pragma unroll
      for (int n = 0; n < NR; ++n)
        bfr[kq][n] = *(const bf16x8*)(lds + boff[n] + ((kc ^ bs7[n]) << 3));
    }
#pragma unroll
    for (int kq = 0; kq < 2; ++kq)
#pragma unroll
      for (int m = 0; m < 4; ++m)
#pragma unroll
        for (int n = 0; n < NR; ++n)
          acc[m][n] = __builtin_amdgcn_mfma_f32_16x16x32_bf16(af[kq][m], bfr[kq][n],
                                                              acc[m][n], 0, 0, 0);
    __syncthreads();
  }

  // C/D layout: col = lane&15, row = (lane>>4)*4 + j
#pragma unroll
  for (int m = 0; m < 4; ++m) {
    const int r0 = row0 + wrow * 64 + m * 16 + lg * 4;
#pragma unroll
    for (int n = 0; n < NR; ++n) {
      const int c = col0 + wcol * (BN_T / 2) + n * 16 + lr;
      if (NCHK && c >= N) continue;
      const float bv = BIAS ? bias[c] : 0.f;
#pragma unroll
      for (int j = 0; j < 4; ++j) {
        float v = acc[m][n][j] + bv;
        const long off = (long)(r0 + j) * N + c;
        if (OBF) ((u16*)Cv)[off] = f2bf(v);
        else if (RES) ((float*)Cv)[off] += v;
        else ((float*)Cv)[off] = v;
      }
    }
  }
}

// one-shot conversion of x + all weights to bf16
// vec4 counts: x 262144 | embed_w 8192 | in_w 131072 | out_w 65536 | xproj_w 12288
__global__ __launch_bounds__(256) void megacvt_k(
    const float* __restrict__ x, const float* __restrict__ ew,
    const float* __restrict__ iw, const float* __restrict__ ow,
    const float* __restrict__ xw,
    u16* __restrict__ xb, u16* __restrict__ ewb, u16* __restrict__ iwb,
    u16* __restrict__ owb, u16* __restrict__ xwb) {
  int i = blockIdx.x * 256 + threadIdx.x;
  const float* s; u16* d;
  if (i < 262144) { s = x; d = xb; }
  else if ((i -= 262144) < 8192) { s = ew; d = ewb; }
  else if ((i -= 8192) < 131072) { s = iw; d = iwb; }
  else if ((i -= 131072) < 65536) { s = ow; d = owb; }
  else { i -= 65536; s = xw; d = xwb; }
  float4 v = ((const float4*)s)[i];
  ushort4 o;
  o.x = f2bf(v.x); o.y = f2bf(v.y); o.z = f2bf(v.z); o.w = f2bf(v.w);
  ((ushort4*)d)[i] = o;
}

// rmsnorm, bf16 out (feeds MFMA GEMM)
__global__ __launch_bounds__(256) void rmsnorm_k(const float* __restrict__ h,
                                                 const float* __restrict__ w,
                                                 u16* __restrict__ o) {
  const int t = blockIdx.x, d = threadIdx.x;
  float v = h[t * NDM + d];
  float s = v * v;
#pragma unroll
  for (int off = 32; off >= 1; off >>= 1) s += __shfl_xor(s, off);
  __shared__ float red[4];
  if ((d & 63) == 0) red[d >> 6] = s;
  __syncthreads();
  float tot = red[0] + red[1] + red[2] + red[3];
  o[t * NDM + d] = f2bf(v * rsqrtf(tot * (1.f / NDM) + 1e-6f) * w[d]);
}

// u2 = silu(depthwise causal conv(u)); bf16 in/out, u = xz[:, :512]
__global__ __launch_bounds__(256) void conv_silu_k(const u16* __restrict__ xzb,
                                                   const float* __restrict__ cw,
                                                   const float* __restrict__ cb,
                                                   u16* __restrict__ u2b) {
  const int t = blockIdx.x, l = t & (LSEQ - 1);
#pragma unroll
  for (int half = 0; half < 2; ++half) {
    const int c = threadIdx.x + half * 256;
    float acc = cb[c];
#pragma unroll
    for (int k = 0; k < 4; ++k) {
      int lp = l - 3 + k;
      if (lp >= 0) acc = fmaf(bf2f(xzb[(t - 3 + k) * 1024 + c]), cw[c * 4 + k], acc);
    }
    u2b[t * NDI + c] = f2bf(acc * sigmoidf_(acc));
  }
}

// ---- chunked parallel scan, thread-per-(b,c,d), 16 states in regs,
// dt-projection + softplus fused (K=16 dot, dbc dt-row is block-uniform) ----

__global__ __launch_bounds__(256) void scanA(const u16* __restrict__ u2b,
                                             const float* __restrict__ dbc,
                                             const float* __restrict__ dtw,
                                             const float* __restrict__ dtbv,
                                             const float* __restrict__ Alog,
                                             float* __restrict__ sEnd,
                                             float* __restrict__ prodA) {
  const int d = ((blockIdx.x & 1) << 8) + threadIdx.x;
  const int cb = blockIdx.x >> 1;
  const int c = cb & (NCH - 1), b = cb >> 6;
  float Ac[16], dtr[16];
#pragma unroll
  for (int q = 0; q < 4; ++q) {
    float4 v = *(const float4*)(Alog + d * NDS + q * 4);
    Ac[q * 4 + 0] = -__expf(v.x); Ac[q * 4 + 1] = -__expf(v.y);
    Ac[q * 4 + 2] = -__expf(v.z); Ac[q * 4 + 3] = -__expf(v.w);
    float4 w = *(const float4*)(dtw + d * NDR + q * 4);
    dtr[q * 4 + 0] = w.x; dtr[q * 4 + 1] = w.y; dtr[q * 4 + 2] = w.z; dtr[q * 4 + 3] = w.w;
  }
  const float dtb_d = dtbv[d];
  float s[16] = {};
  float dacc = 0.f;
  int t = b * LSEQ + c * CHUNK;
  for (int j = 0; j < CHUNK; ++j, ++t) {
    float dsum = dtb_d;
#pragma unroll
    for (int q = 0; q < 4; ++q) {
      float4 dv = *(const float4*)(dbc + t * 48 + q * 4);
      dsum = fmaf(dv.x, dtr[q * 4 + 0], dsum); dsum = fmaf(dv.y, dtr[q * 4 + 1], dsum);
      dsum = fmaf(dv.z, dtr[q * 4 + 2], dsum); dsum = fmaf(dv.w, dtr[q * 4 + 3], dsum);
    }
    const float dl = softplus_(dsum);
    const float ul = bf2f(u2b[t * NDI + d]);
    const float du = dl * ul;
    dacc += dl;
#pragma unroll
    for (int q = 0; q < 4; ++q) {
      float4 Bv = *(const float4*)(dbc + t * 48 + NDR + q * 4);
      float Be[4] = {Bv.x, Bv.y, Bv.z, Bv.w};
#pragma unroll
      for (int e = 0; e < 4; ++e) {
        int n = q * 4 + e;
        s[n] = fmaf(__expf(dl * Ac[n]), s[n], du * Be[e]);
      }
    }
  }
  const long base = ((long)((b * NCH + c) * NDI + d)) * NDS;
#pragma unroll
  for (int q = 0; q < 4; ++q) {
    *(float4*)(sEnd + base + q * 4) =
        make_float4(s[q * 4], s[q * 4 + 1], s[q * 4 + 2], s[q * 4 + 3]);
    *(float4*)(prodA + base + q * 4) =
        make_float4(__expf(Ac[q * 4] * dacc), __expf(Ac[q * 4 + 1] * dacc),
                    __expf(Ac[q * 4 + 2] * dacc), __expf(Ac[q * 4 + 3] * dacc));
  }
}

__global__ __launch_bounds__(256) void scanB(const float* __restrict__ sEnd,
                                             const float* __restrict__ prodA,
                                             float* __restrict__ carry) {
  const int g = blockIdx.x * 256 + threadIdx.x;   // (b, d*16+n)
  const int dn = g & (NDI * NDS - 1);
  const int b = g >> 13;
  float h = 0.f;
  const long base = (long)b * NCH * NDI * NDS + dn;
#pragma unroll 4
  for (int c = 0; c < NCH; ++c) {
    const long idx = base + (long)c * NDI * NDS;
    carry[idx] = h;
    h = fmaf(prodA[idx], h, sEnd[idx]);
  }
}

__global__ __launch_bounds__(256) void scanC(const u16* __restrict__ u2b,
                                             const float* __restrict__ dbc,
                                             const u16* __restrict__ xzb,
                                             const float* __restrict__ dtw,
                                             const float* __restrict__ dtbv,
                                             const float* __restrict__ Alog,
                                             const float* __restrict__ Dp,
                                             const float* __restrict__ carry,
                                             u16* __restrict__ y) {
  const int d = ((blockIdx.x & 1) << 8) + threadIdx.x;
  const int cb = blockIdx.x >> 1;
  const int c = cb & (NCH - 1), b = cb >> 6;
  float Ac[16], dtr[16];
#pragma unroll
  for (int q = 0; q < 4; ++q) {
    float4 v = *(const float4*)(Alog + d * NDS + q * 4);
    Ac[q * 4 + 0] = -__expf(v.x); Ac[q * 4 + 1] = -__expf(v.y);
    Ac[q * 4 + 2] = -__expf(v.z); Ac[q * 4 + 3] = -__expf(v.w);
    float4 w = *(const float4*)(dtw + d * NDR + q * 4);
    dtr[q * 4 + 0] = w.x; dtr[q * 4 + 1] = w.y; dtr[q * 4 + 2] = w.z; dtr[q * 4 + 3] = w.w;
  }
  const float dtb_d = dtbv[d];
  const float Dv = Dp[d];
  float s[16];
  const long base = ((long)((b * NCH + c) * NDI + d)) * NDS;
#pragma unroll
  for (int q = 0; q < 4; ++q) {
    float4 v = *(const float4*)(carry + base + q * 4);
    s[q * 4 + 0] = v.x; s[q * 4 + 1] = v.y; s[q * 4 + 2] = v.z; s[q * 4 + 3] = v.w;
  }
  int t = b * LSEQ + c * CHUNK;
  for (int j = 0; j < CHUNK; ++j, ++t) {
    float dsum = dtb_d;
#pragma unroll
    for (int q = 0; q < 4; ++q) {
      float4 dv = *(const float4*)(dbc + t * 48 + q * 4);
      dsum = fmaf(dv.x, dtr[q * 4 + 0], dsum); dsum = fmaf(dv.y, dtr[q * 4 + 1], dsum);
      dsum = fmaf(dv.z, dtr[q * 4 + 2], dsum); dsum = fmaf(dv.w, dtr[q * 4 + 3], dsum);
    }
    const float dl = softplus_(dsum);
    const float ul = bf2f(u2b[t * NDI + d]);
    const float du = dl * ul;
    float p = 0.f;
#pragma unroll
    for (int q = 0; q < 4; ++q) {
      float4 Bv = *(const float4*)(dbc + t * 48 + NDR + q * 4);
      float4 Cv = *(const float4*)(dbc + t * 48 + NDR + NDS + q * 4);
      float Be[4] = {Bv.x, Bv.y, Bv.z, Bv.w};
      float Ce[4] = {Cv.x, Cv.y, Cv.z, Cv.w};
#pragma unroll
      for (int e = 0; e < 4; ++e) {
        int n = q * 4 + e;
        s[n] = fmaf(__expf(dl * Ac[n]), s[n], du * Be[e]);
        p = fmaf(s[n], Ce[e], p);
      }
    }
    const float zl = bf2f(xzb[t * 1024 + NDI + d]);
    y[t * NDI + d] = f2bf((p + ul * Dv) * zl * sigmoidf_(zl));
  }
}

// fused final rmsnorm + mean-pool: block = 32 rows, wave per row (4 elems/lane)
__global__ __launch_bounds__(256) void finalpool_k(const float* __restrict__ h,
                                                   const float* __restrict__ w,
                                                   float* __restrict__ pooled) {
  const int wave = threadIdx.x >> 6, lane = threadIdx.x & 63;
  const int t0 = blockIdx.x * 32;
  const int b = t0 >> 11;
  const float4 wv = ((const float4*)w)[lane];
  float a0 = 0.f, a1 = 0.f, a2 = 0.f, a3 = 0.f;
  for (int r = wave; r < 32; r += 4) {
    const float4 v = ((const float4*)(h + (long)(t0 + r) * NDM))[lane];
    float ss = v.x * v.x + v.y * v.y + v.z * v.z + v.w * v.w;
#pragma unroll
    for (int off = 32; off >= 1; off >>= 1) ss += __shfl_xor(ss, off);
    const float rs = rsqrtf(ss * (1.f / NDM) + 1e-6f);
    a0 = fmaf(v.x * rs, wv.x, a0); a1 = fmaf(v.y * rs, wv.y, a1);
    a2 = fmaf(v.z * rs, wv.z, a2); a3 = fmaf(v.w * rs, wv.w, a3);
  }
  __shared__ float red[4][NDM];
  red[wave][lane * 4 + 0] = a0; red[wave][lane * 4 + 1] = a1;
  red[wave][lane * 4 + 2] = a2; red[wave][lane * 4 + 3] = a3;
  __syncthreads();
  if (wave == 0) {
#pragma unroll
    for (int e = 0; e < 4; ++e) {
      const int dc = lane * 4 + e;
      const float sum = red[0][dc] + red[1][dc] + red[2][dc] + red[3][dc];
      atomicAdd(pooled + b * NDM + dc, sum * (1.f / LSEQ));
    }
  }
}

__global__ __launch_bounds__(128) void bias_k(const float* __restrict__ pooled,
                                              const float* __restrict__ pw,
                                              const float* __restrict__ pb,
                                              float* __restrict__ bv) {
  const int b = blockIdx.x, f = threadIdx.x;
  float acc = pb[f];
  for (int dd = 0; dd < NDM; ++dd) acc = fmaf(pooled[b * NDM + dd], pw[f * NDM + dd], acc);
  bv[b * NF + f] = acc;
}

__global__ __launch_bounds__(256) void addout_k(const float* __restrict__ x,
                                                const float* __restrict__ bv,
                                                float* __restrict__ out) {
  const int i4 = blockIdx.x * 256 + threadIdx.x;
  const float4 xv = ((const float4*)x)[i4];
  const int trow = i4 >> 5;
  const int b = trow >> 11;
  const int f4 = i4 & 31;
  const float4 bb = ((const float4*)bv)[b * 32 + f4];
  float4 o;
  o.x = xv.x + bb.x; o.y = xv.y + bb.y; o.z = xv.z + bb.z; o.w = xv.w + bb.w;
  ((float4*)out)[i4] = o;
}

extern "C" void kernel_launch(void* const* d_in, const int* in_sizes, int n_in,
                              void* d_out, int out_size, void* d_ws, size_t ws_size,
                              hipStream_t stream) {
  const float* x       = (const float*)d_in[0];
  const float* embed_w = (const float*)d_in[1];
  const float* embed_b = (const float*)d_in[2];
  const float* in_w    = (const float*)d_in[3];
  const float* conv_w  = (const float*)d_in[4];
  const float* conv_b  = (const float*)d_in[5];
  const float* xproj_w = (const float*)d_in[6];
  const float* dt_w    = (const float*)d_in[7];
  const float* dt_b    = (const float*)d_in[8];
  const float* A_log   = (const float*)d_in[9];
  const float* Dw      = (const float*)d_in[10];
  const float* out_w   = (const float*)d_in[11];
  const float* norm_w  = (const float*)d_in[12];
  const float* fnorm_w = (const float*)d_in[13];
  const float* proj_w  = (const float*)d_in[14];
  const float* proj_b  = (const float*)d_in[15];

  // workspace layout (f32 units), ~64.1 MB total (ws >= 97 MB proven R1-3).
  // R4 BUG FIX: u2b needs 8192*512 u16 = 2,097,152 f32-equivalents (was 1M).
  float* ws     = (float*)d_ws;
  float* h      = ws;                            // 2M f32
  float* hnr    = h    + 2097152;                // 2M f32: carry (f32) / hnb (bf16, 1M f32-eq)
  float* xzr    = hnr  + 2097152;                // 4M f32: xzb bf16 (8M elems, exact)
  float* u2r    = xzr  + 4194304;                // 2M f32: u2b bf16 (4M elems, exact)
  float* ybr    = u2r  + 2097152;                // 4M f32: sEnd|prodA / ybb bf16 (2M f32-eq)
  float* dbc    = ybr  + 4194304;                // 393216 f32
  float* xbr    = dbc  + 393216;                 // 512K f32: xb bf16 (1M elems, exact)
  float* inwr   = xbr  + 524288;                 // 262144 f32: in_w bf16 (both layers, exact)
  float* owr    = inwr + 262144;                 // 131072 f32: out_w bf16 (exact)
  float* xpwr   = owr  + 131072;                 // 24576 f32: xproj_w bf16 (exact)
  float* ewr    = xpwr + 24576;                  // 16384 f32: embed_w bf16 (exact)
  float* pooled = ewr  + 16384;                  // 1024
  float* bv     = pooled + 1024;                 // 512

  const long SCN = (long)BATCH * NCH * NDI * NDS;  // 2,097,152
  float* sEnd  = ybr;
  float* prodA = ybr + SCN;
  float* carry = hnr;
  u16* ybb  = (u16*)ybr;
  u16* hnb  = (u16*)hnr;
  u16* xzb  = (u16*)xzr;
  u16* u2b  = (u16*)u2r;
  u16* xb   = (u16*)xbr;
  u16* inwb = (u16*)inwr;
  u16* owb  = (u16*)owr;
  u16* xpwb = (u16*)xpwr;
  u16* ewb  = (u16*)ewr;

  // one-shot bf16 conversion of x + all weights (479232 vec4 / 256 = 1872 blocks)
  megacvt_k<<<1872, 256, 0, stream>>>(x, embed_w, in_w, out_w, xproj_w,
                                      xb, ewb, inwb, owb, xpwb);
  // h = x @ embed_w^T + embed_b   (MFMA, 8192x256x128)
  gemm_bf16<64, true, false, false, false><<<dim3(4, 64), 256, 0, stream>>>(
      xb, ewb, embed_b, h, NDM, NF);

  for (int i = 0; i < 2; ++i) {
    const float* cw  = conv_w + (long)i * NDI * 4;
    const float* cb  = conv_b + (long)i * NDI;
    const float* dtw = dt_w   + (long)i * NDI * NDR;
    const float* dtb = dt_b   + (long)i * NDI;
    const float* al  = A_log  + (long)i * NDI * NDS;
    const float* dd  = Dw     + (long)i * NDI;

    rmsnorm_k<<<TTOK, 256, 0, stream>>>(h, norm_w + i * NDM, hnb);
    // xz = hn @ in_w^T  (MFMA, 8192x1024x256, bf16 out)
    gemm_bf16<128, false, false, true, false><<<dim3(8, 64), 256, 0, stream>>>(
        hnb, inwb + (long)i * 2 * NDI * NDM, nullptr, xzb, 1024, NDM);
    conv_silu_k<<<TTOK, 256, 0, stream>>>(xzb, cw, cb, u2b);
    // dbc = u2 @ xproj_w^T  (MFMA, 8192x48x512, N-clamped)
    gemm_bf16<64, false, false, false, true><<<dim3(1, 64), 256, 0, stream>>>(
        u2b, xpwb + (long)i * 48 * NDI, nullptr, dbc, 48, NDI);
    // chunked parallel scan (dt-proj + softplus fused)
    scanA<<<BATCH * NCH * 2, 256, 0, stream>>>(u2b, dbc, dtw, dtb, al, sEnd, prodA);
    scanB<<<BATCH * NDI * NDS / 256, 256, 0, stream>>>(sEnd, prodA, carry);
    scanC<<<BATCH * NCH * 2, 256, 0, stream>>>(u2b, dbc, xzb, dtw, dtb, al, dd,
                                               carry, ybb);
    // h += yb @ out_w^T  (MFMA, 8192x256x512)
    gemm_bf16<64, false, true, false, false><<<dim3(4, 64), 256, 0, stream>>>(
        ybb, owb + (long)i * NDM * NDI, nullptr, h, NDM, NDI);
  }

  hipMemsetAsync(pooled, 0, BATCH * NDM * sizeof(float), stream);
  finalpool_k<<<TTOK / 32, 256, 0, stream>>>(h, fnorm_w, pooled);
  bias_k<<<BATCH, 128, 0, stream>>>(pooled, proj_w, proj_b, bv);
  addout_k<<<TTOK * NF / 4 / 256, 256, 0, stream>>>(x, bv, (float*)d_out);
}

// Round 7
// 306.935 us; speedup vs baseline: 10.6619x; 1.1130x over previous
//
#include <hip/hip_runtime.h>

#define TTOK 8192   // B*L
#define BATCH 4
#define LSEQ 2048
#define NDM 256
#define NF 128
#define NDI 512
#define NDS 16
#define NDR 16
#define CHUNK 16
#define NCH (LSEQ / CHUNK)   // 128
#define NCH_LOG 7

typedef unsigned short u16;
typedef __attribute__((ext_vector_type(8))) short bf16x8;
typedef __attribute__((ext_vector_type(4))) float f32x4;

__device__ __forceinline__ float sigmoidf_(float x) { return 1.f / (1.f + __expf(-x)); }

__device__ __forceinline__ u16 f2bf(float f) {  // RTN-even
  unsigned u = __float_as_uint(f);
  u += 0x7FFF + ((u >> 16) & 1);
  return (u16)(u >> 16);
}
__device__ __forceinline__ float bf2f(u16 v) {
  return __uint_as_float((unsigned)v << 16);
}
__device__ __forceinline__ float softplus_(float x) {  // stable
  return fmaxf(x, 0.f) + __logf(1.f + __expf(-fabsf(x)));
}

// ---------------- bf16 MFMA GEMM ----------------
// C[m,n] = A[m,:]·W[n,:] (+bias) (+= if RES). A:[M][K] bf16, W:[N][K] bf16.
// Tile 128 x BN_T, BK=64, 4 waves (2x2). OBF: C is bf16. NCHK: clamp W rows,
// skip C cols >= N. LDS rows: 0..127 A-tile, 128.. W-tile; 64 bf16/row.
// XOR swizzle on 16B chunks (pre-swizzled global source, swizzled ds_read).
template<int BN_T, bool BIAS, bool RES, bool OBF, bool NCHK>
__global__ __launch_bounds__(256) void gemm_bf16(const u16* __restrict__ A,
                                                 const u16* __restrict__ W,
                                                 const float* __restrict__ bias,
                                                 void* __restrict__ Cv,
                                                 int N, int K) {
  constexpr int NR = BN_T / 32;
  constexpr int ROWS = 128 + BN_T;
  constexpr int CPW = (ROWS / 8) / 4;
  __shared__ u16 lds[ROWS * 64];
  const int tid = threadIdx.x;
  const int wave = tid >> 6, lane = tid & 63;
  const int wrow = wave >> 1, wcol = wave & 1;
  const int lr = lane & 15, lg = lane >> 4;
  const int row0 = blockIdx.y * 128, col0 = blockIdx.x * BN_T;

  const u16* srcp[CPW];
  u16* ldsp[CPW];
#pragma unroll
  for (int i = 0; i < CPW; ++i) {
    const int q = wave * CPW + i;
    const int row = q * 8 + (lane >> 3);
    const int ck = lane & 7;
    const int sck = ck ^ (row & 7);
    long grow;
    if (row < 128) grow = (long)(row0 + row) * K;
    else {
      int wr = row - 128;
      if (NCHK && wr >= N) wr = N - 1;
      grow = (long)(col0 + wr) * K;
    }
    srcp[i] = ((row < 128) ? A : W) + grow + sck * 8;
    ldsp[i] = (u16*)&lds[q * 512];
  }

  int aoff[4], as7[4], boff[NR], bs7[NR];
#pragma unroll
  for (int m = 0; m < 4; ++m) {
    const int r = wrow * 64 + m * 16 + lr;
    aoff[m] = r * 64; as7[m] = r & 7;
  }
#pragma unroll
  for (int n = 0; n < NR; ++n) {
    const int r = 128 + wcol * (BN_T / 2) + n * 16 + lr;
    boff[n] = r * 64; bs7[n] = r & 7;
  }

  f32x4 acc[4][NR];
#pragma unroll
  for (int m = 0; m < 4; ++m)
#pragma unroll
    for (int n = 0; n < NR; ++n) acc[m][n] = (f32x4)(0.f);

  for (int k0 = 0; k0 < K; k0 += 64) {
#pragma unroll
    for (int i = 0; i < CPW; ++i)
      __builtin_amdgcn_global_load_lds(
          (const __attribute__((address_space(1))) unsigned int*)(srcp[i] + k0),
          (__attribute__((address_space(3))) unsigned int*)(ldsp[i]), 16, 0, 0);
    __syncthreads();

    bf16x8 af[2][4], bfr[2][NR];
#pragma unroll
    for (int kq = 0; kq < 2; ++kq) {
      const int kc = kq * 4 + lg;
#pragma unroll
      for (int m = 0; m < 4; ++m)
        af[kq][m] = *(const bf16x8*)(lds + aoff[m] + ((kc ^ as7[m]) << 3));
#pragma unroll
      for (int n = 0; n < NR; ++n)
        bfr[kq][n] = *(const bf16x8*)(lds + boff[n] + ((kc ^ bs7[n]) << 3));
    }
#pragma unroll
    for (int kq = 0; kq < 2; ++kq)
#pragma unroll
      for (int m = 0; m < 4; ++m)
#pragma unroll
        for (int n = 0; n < NR; ++n)
          acc[m][n] = __builtin_amdgcn_mfma_f32_16x16x32_bf16(af[kq][m], bfr[kq][n],
                                                              acc[m][n], 0, 0, 0);
    __syncthreads();
  }

  // C/D layout: col = lane&15, row = (lane>>4)*4 + j
#pragma unroll
  for (int m = 0; m < 4; ++m) {
    const int r0 = row0 + wrow * 64 + m * 16 + lg * 4;
#pragma unroll
    for (int n = 0; n < NR; ++n) {
      const int c = col0 + wcol * (BN_T / 2) + n * 16 + lr;
      if (NCHK && c >= N) continue;
      const float bv = BIAS ? bias[c] : 0.f;
#pragma unroll
      for (int j = 0; j < 4; ++j) {
        float v = acc[m][n][j] + bv;
        const long off = (long)(r0 + j) * N + c;
        if (OBF) ((u16*)Cv)[off] = f2bf(v);
        else if (RES) ((float*)Cv)[off] += v;
        else ((float*)Cv)[off] = v;
      }
    }
  }
}

// one-shot conversion of x + all weights to bf16
// vec4 counts: x 262144 | embed_w 8192 | in_w 131072 | out_w 65536 | xproj_w 12288
__global__ __launch_bounds__(256) void megacvt_k(
    const float* __restrict__ x, const float* __restrict__ ew,
    const float* __restrict__ iw, const float* __restrict__ ow,
    const float* __restrict__ xw,
    u16* __restrict__ xb, u16* __restrict__ ewb, u16* __restrict__ iwb,
    u16* __restrict__ owb, u16* __restrict__ xwb) {
  int i = blockIdx.x * 256 + threadIdx.x;
  const float* s; u16* d;
  if (i < 262144) { s = x; d = xb; }
  else if ((i -= 262144) < 8192) { s = ew; d = ewb; }
  else if ((i -= 8192) < 131072) { s = iw; d = iwb; }
  else if ((i -= 131072) < 65536) { s = ow; d = owb; }
  else { i -= 65536; s = xw; d = xwb; }
  float4 v = ((const float4*)s)[i];
  ushort4 o;
  o.x = f2bf(v.x); o.y = f2bf(v.y); o.z = f2bf(v.z); o.w = f2bf(v.w);
  ((ushort4*)d)[i] = o;
}

// rmsnorm, bf16 out (feeds MFMA GEMM)
__global__ __launch_bounds__(256) void rmsnorm_k(const float* __restrict__ h,
                                                 const float* __restrict__ w,
                                                 u16* __restrict__ o) {
  const int t = blockIdx.x, d = threadIdx.x;
  float v = h[t * NDM + d];
  float s = v * v;
#pragma unroll
  for (int off = 32; off >= 1; off >>= 1) s += __shfl_xor(s, off);
  __shared__ float red[4];
  if ((d & 63) == 0) red[d >> 6] = s;
  __syncthreads();
  float tot = red[0] + red[1] + red[2] + red[3];
  o[t * NDM + d] = f2bf(v * rsqrtf(tot * (1.f / NDM) + 1e-6f) * w[d]);
}

// u2 = silu(depthwise causal conv(u)); bf16 in/out, u = xz[:, :512]
__global__ __launch_bounds__(256) void conv_silu_k(const u16* __restrict__ xzb,
                                                   const float* __restrict__ cw,
                                                   const float* __restrict__ cb,
                                                   u16* __restrict__ u2b) {
  const int t = blockIdx.x, l = t & (LSEQ - 1);
#pragma unroll
  for (int half = 0; half < 2; ++half) {
    const int c = threadIdx.x + half * 256;
    float acc = cb[c];
#pragma unroll
    for (int k = 0; k < 4; ++k) {
      int lp = l - 3 + k;
      if (lp >= 0) acc = fmaf(bf2f(xzb[(t - 3 + k) * 1024 + c]), cw[c * 4 + k], acc);
    }
    u2b[t * NDI + c] = f2bf(acc * sigmoidf_(acc));
  }
}

// ---- chunked parallel scan, thread-per-(b,c,d), 16 states in regs,
// dt-projection + softplus fused (K=16 dot, dbc dt-row is block-uniform) ----

__global__ __launch_bounds__(256) void scanA(const u16* __restrict__ u2b,
                                             const float* __restrict__ dbc,
                                             const float* __restrict__ dtw,
                                             const float* __restrict__ dtbv,
                                             const float* __restrict__ Alog,
                                             float* __restrict__ sEnd,
                                             float* __restrict__ prodA) {
  const int d = ((blockIdx.x & 1) << 8) + threadIdx.x;
  const int cb = blockIdx.x >> 1;
  const int c = cb & (NCH - 1), b = cb >> NCH_LOG;
  float Ac[16], dtr[16];
#pragma unroll
  for (int q = 0; q < 4; ++q) {
    float4 v = *(const float4*)(Alog + d * NDS + q * 4);
    Ac[q * 4 + 0] = -__expf(v.x); Ac[q * 4 + 1] = -__expf(v.y);
    Ac[q * 4 + 2] = -__expf(v.z); Ac[q * 4 + 3] = -__expf(v.w);
    float4 w = *(const float4*)(dtw + d * NDR + q * 4);
    dtr[q * 4 + 0] = w.x; dtr[q * 4 + 1] = w.y; dtr[q * 4 + 2] = w.z; dtr[q * 4 + 3] = w.w;
  }
  const float dtb_d = dtbv[d];
  float s[16] = {};
  float dacc = 0.f;
  int t = b * LSEQ + c * CHUNK;
  for (int j = 0; j < CHUNK; ++j, ++t) {
    float dsum = dtb_d;
#pragma unroll
    for (int q = 0; q < 4; ++q) {
      float4 dv = *(const float4*)(dbc + t * 48 + q * 4);
      dsum = fmaf(dv.x, dtr[q * 4 + 0], dsum); dsum = fmaf(dv.y, dtr[q * 4 + 1], dsum);
      dsum = fmaf(dv.z, dtr[q * 4 + 2], dsum); dsum = fmaf(dv.w, dtr[q * 4 + 3], dsum);
    }
    const float dl = softplus_(dsum);
    const float ul = bf2f(u2b[t * NDI + d]);
    const float du = dl * ul;
    dacc += dl;
#pragma unroll
    for (int q = 0; q < 4; ++q) {
      float4 Bv = *(const float4*)(dbc + t * 48 + NDR + q * 4);
      float Be[4] = {Bv.x, Bv.y, Bv.z, Bv.w};
#pragma unroll
      for (int e = 0; e < 4; ++e) {
        int n = q * 4 + e;
        s[n] = fmaf(__expf(dl * Ac[n]), s[n], du * Be[e]);
      }
    }
  }
  const long base = ((long)((b * NCH + c) * NDI + d)) * NDS;
#pragma unroll
  for (int q = 0; q < 4; ++q) {
    *(float4*)(sEnd + base + q * 4) =
        make_float4(s[q * 4], s[q * 4 + 1], s[q * 4 + 2], s[q * 4 + 3]);
    *(float4*)(prodA + base + q * 4) =
        make_float4(__expf(Ac[q * 4] * dacc), __expf(Ac[q * 4 + 1] * dacc),
                    __expf(Ac[q * 4 + 2] * dacc), __expf(Ac[q * 4 + 3] * dacc));
  }
}

// Phase B, IN-PLACE: sp holds sEnd on entry, carry (chunk start states) on exit.
// Per idx: read sEnd/prodA before overwriting with the pre-update carry. Each
// idx is touched by exactly one thread, so in-place is race-free.
__global__ __launch_bounds__(256) void scanB(float* __restrict__ sp,
                                             const float* __restrict__ prodA) {
  const int g = blockIdx.x * 256 + threadIdx.x;   // (b, d*16+n)
  const int dn = g & (NDI * NDS - 1);
  const int b = g >> 13;
  float h = 0.f;
  const long base = (long)b * NCH * NDI * NDS + dn;
#pragma unroll 8
  for (int c = 0; c < NCH; ++c) {
    const long idx = base + (long)c * NDI * NDS;
    const float pe = sp[idx];
    const float pa = prodA[idx];
    sp[idx] = h;
    h = fmaf(pa, h, pe);
  }
}

__global__ __launch_bounds__(256) void scanC(const u16* __restrict__ u2b,
                                             const float* __restrict__ dbc,
                                             const u16* __restrict__ xzb,
                                             const float* __restrict__ dtw,
                                             const float* __restrict__ dtbv,
                                             const float* __restrict__ Alog,
                                             const float* __restrict__ Dp,
                                             const float* __restrict__ carry,
                                             u16* __restrict__ y) {
  const int d = ((blockIdx.x & 1) << 8) + threadIdx.x;
  const int cb = blockIdx.x >> 1;
  const int c = cb & (NCH - 1), b = cb >> NCH_LOG;
  float Ac[16], dtr[16];
#pragma unroll
  for (int q = 0; q < 4; ++q) {
    float4 v = *(const float4*)(Alog + d * NDS + q * 4);
    Ac[q * 4 + 0] = -__expf(v.x); Ac[q * 4 + 1] = -__expf(v.y);
    Ac[q * 4 + 2] = -__expf(v.z); Ac[q * 4 + 3] = -__expf(v.w);
    float4 w = *(const float4*)(dtw + d * NDR + q * 4);
    dtr[q * 4 + 0] = w.x; dtr[q * 4 + 1] = w.y; dtr[q * 4 + 2] = w.z; dtr[q * 4 + 3] = w.w;
  }
  const float dtb_d = dtbv[d];
  const float Dv = Dp[d];
  float s[16];
  const long base = ((long)((b * NCH + c) * NDI + d)) * NDS;
#pragma unroll
  for (int q = 0; q < 4; ++q) {
    float4 v = *(const float4*)(carry + base + q * 4);
    s[q * 4 + 0] = v.x; s[q * 4 + 1] = v.y; s[q * 4 + 2] = v.z; s[q * 4 + 3] = v.w;
  }
  int t = b * LSEQ + c * CHUNK;
  for (int j = 0; j < CHUNK; ++j, ++t) {
    float dsum = dtb_d;
#pragma unroll
    for (int q = 0; q < 4; ++q) {
      float4 dv = *(const float4*)(dbc + t * 48 + q * 4);
      dsum = fmaf(dv.x, dtr[q * 4 + 0], dsum); dsum = fmaf(dv.y, dtr[q * 4 + 1], dsum);
      dsum = fmaf(dv.z, dtr[q * 4 + 2], dsum); dsum = fmaf(dv.w, dtr[q * 4 + 3], dsum);
    }
    const float dl = softplus_(dsum);
    const float ul = bf2f(u2b[t * NDI + d]);
    const float du = dl * ul;
    float p = 0.f;
#pragma unroll
    for (int q = 0; q < 4; ++q) {
      float4 Bv = *(const float4*)(dbc + t * 48 + NDR + q * 4);
      float4 Cv = *(const float4*)(dbc + t * 48 + NDR + NDS + q * 4);
      float Be[4] = {Bv.x, Bv.y, Bv.z, Bv.w};
      float Ce[4] = {Cv.x, Cv.y, Cv.z, Cv.w};
#pragma unroll
      for (int e = 0; e < 4; ++e) {
        int n = q * 4 + e;
        s[n] = fmaf(__expf(dl * Ac[n]), s[n], du * Be[e]);
        p = fmaf(s[n], Ce[e], p);
      }
    }
    const float zl = bf2f(xzb[t * 1024 + NDI + d]);
    y[t * NDI + d] = f2bf((p + ul * Dv) * zl * sigmoidf_(zl));
  }
}

// fused final rmsnorm + mean-pool: block = 32 rows, wave per row (4 elems/lane)
__global__ __launch_bounds__(256) void finalpool_k(const float* __restrict__ h,
                                                   const float* __restrict__ w,
                                                   float* __restrict__ pooled) {
  const int wave = threadIdx.x >> 6, lane = threadIdx.x & 63;
  const int t0 = blockIdx.x * 32;
  const int b = t0 >> 11;
  const float4 wv = ((const float4*)w)[lane];
  float a0 = 0.f, a1 = 0.f, a2 = 0.f, a3 = 0.f;
  for (int r = wave; r < 32; r += 4) {
    const float4 v = ((const float4*)(h + (long)(t0 + r) * NDM))[lane];
    float ss = v.x * v.x + v.y * v.y + v.z * v.z + v.w * v.w;
#pragma unroll
    for (int off = 32; off >= 1; off >>= 1) ss += __shfl_xor(ss, off);
    const float rs = rsqrtf(ss * (1.f / NDM) + 1e-6f);
    a0 = fmaf(v.x * rs, wv.x, a0); a1 = fmaf(v.y * rs, wv.y, a1);
    a2 = fmaf(v.z * rs, wv.z, a2); a3 = fmaf(v.w * rs, wv.w, a3);
  }
  __shared__ float red[4][NDM];
  red[wave][lane * 4 + 0] = a0; red[wave][lane * 4 + 1] = a1;
  red[wave][lane * 4 + 2] = a2; red[wave][lane * 4 + 3] = a3;
  __syncthreads();
  if (wave == 0) {
#pragma unroll
    for (int e = 0; e < 4; ++e) {
      const int dc = lane * 4 + e;
      const float sum = red[0][dc] + red[1][dc] + red[2][dc] + red[3][dc];
      atomicAdd(pooled + b * NDM + dc, sum * (1.f / LSEQ));
    }
  }
}

__global__ __launch_bounds__(128) void bias_k(const float* __restrict__ pooled,
                                              const float* __restrict__ pw,
                                              const float* __restrict__ pb,
                                              float* __restrict__ bv) {
  const int b = blockIdx.x, f = threadIdx.x;
  float acc = pb[f];
  for (int dd = 0; dd < NDM; ++dd) acc = fmaf(pooled[b * NDM + dd], pw[f * NDM + dd], acc);
  bv[b * NF + f] = acc;
}

__global__ __launch_bounds__(256) void addout_k(const float* __restrict__ x,
                                                const float* __restrict__ bv,
                                                float* __restrict__ out) {
  const int i4 = blockIdx.x * 256 + threadIdx.x;
  const float4 xv = ((const float4*)x)[i4];
  const int trow = i4 >> 5;
  const int b = trow >> 11;
  const int f4 = i4 & 31;
  const float4 bb = ((const float4*)bv)[b * 32 + f4];
  float4 o;
  o.x = xv.x + bb.x; o.y = xv.y + bb.y; o.z = xv.z + bb.z; o.w = xv.w + bb.w;
  ((float4*)out)[i4] = o;
}

extern "C" void kernel_launch(void* const* d_in, const int* in_sizes, int n_in,
                              void* d_out, int out_size, void* d_ws, size_t ws_size,
                              hipStream_t stream) {
  const float* x       = (const float*)d_in[0];
  const float* embed_w = (const float*)d_in[1];
  const float* embed_b = (const float*)d_in[2];
  const float* in_w    = (const float*)d_in[3];
  const float* conv_w  = (const float*)d_in[4];
  const float* conv_b  = (const float*)d_in[5];
  const float* xproj_w = (const float*)d_in[6];
  const float* dt_w    = (const float*)d_in[7];
  const float* dt_b    = (const float*)d_in[8];
  const float* A_log   = (const float*)d_in[9];
  const float* Dw      = (const float*)d_in[10];
  const float* out_w   = (const float*)d_in[11];
  const float* norm_w  = (const float*)d_in[12];
  const float* fnorm_w = (const float*)d_in[13];
  const float* proj_w  = (const float*)d_in[14];
  const float* proj_b  = (const float*)d_in[15];

  // workspace layout (f32 units), ~85.1 MB total (ws >= 97.5 MB proven R1-3).
  // No aliasing this round; every bf16 buffer sized exactly (R4 lesson).
  float* ws     = (float*)d_ws;
  float* h      = ws;                            // 2,097,152 f32
  float* hnr    = h    + 2097152;                // 1,048,576 f32-eq: hnb bf16 (2M elems)
  float* xzr    = hnr  + 1048576;                // 4,194,304 f32-eq: xzb bf16 (8M elems)
  float* u2r    = xzr  + 4194304;                // 2,097,152 f32-eq: u2b bf16 (4M elems)
  float* ybr    = u2r  + 2097152;                // 2,097,152 f32-eq: ybb bf16 (4M elems)
  float* dbc    = ybr  + 2097152;                // 393,216 f32
  float* sEnd   = dbc  + 393216;                 // 4,194,304 f32 (becomes carry in-place)
  float* prodA  = sEnd + 4194304;                // 4,194,304 f32
  float* xbr    = prodA + 4194304;               // 524,288 f32-eq: xb bf16 (1M elems)
  float* inwr   = xbr  + 524288;                 // 262,144 f32-eq: in_w bf16 (both layers)
  float* owr    = inwr + 262144;                 // 131,072 f32-eq: out_w bf16
  float* xpwr   = owr  + 131072;                 // 24,576 f32-eq: xproj_w bf16
  float* ewr    = xpwr + 24576;                  // 16,384 f32-eq: embed_w bf16
  float* pooled = ewr  + 16384;                  // 1024
  float* bv     = pooled + 1024;                 // 512

  u16* ybb  = (u16*)ybr;
  u16* hnb  = (u16*)hnr;
  u16* xzb  = (u16*)xzr;
  u16* u2b  = (u16*)u2r;
  u16* xb   = (u16*)xbr;
  u16* inwb = (u16*)inwr;
  u16* owb  = (u16*)owr;
  u16* xpwb = (u16*)xpwr;
  u16* ewb  = (u16*)ewr;

  // one-shot bf16 conversion of x + all weights (479232 vec4 / 256 = 1872 blocks)
  megacvt_k<<<1872, 256, 0, stream>>>(x, embed_w, in_w, out_w, xproj_w,
                                      xb, ewb, inwb, owb, xpwb);
  // h = x @ embed_w^T + embed_b   (MFMA, 8192x256x128)
  gemm_bf16<64, true, false, false, false><<<dim3(4, 64), 256, 0, stream>>>(
      xb, ewb, embed_b, h, NDM, NF);

  for (int i = 0; i < 2; ++i) {
    const float* cw  = conv_w + (long)i * NDI * 4;
    const float* cb  = conv_b + (long)i * NDI;
    const float* dtw = dt_w   + (long)i * NDI * NDR;
    const float* dtb = dt_b   + (long)i * NDI;
    const float* al  = A_log  + (long)i * NDI * NDS;
    const float* dd  = Dw     + (long)i * NDI;

    rmsnorm_k<<<TTOK, 256, 0, stream>>>(h, norm_w + i * NDM, hnb);
    // xz = hn @ in_w^T  (MFMA, 8192x1024x256, bf16 out)
    gemm_bf16<128, false, false, true, false><<<dim3(8, 64), 256, 0, stream>>>(
        hnb, inwb + (long)i * 2 * NDI * NDM, nullptr, xzb, 1024, NDM);
    conv_silu_k<<<TTOK, 256, 0, stream>>>(xzb, cw, cb, u2b);
    // dbc = u2 @ xproj_w^T  (MFMA, 8192x48x512, N-clamped)
    gemm_bf16<64, false, false, false, true><<<dim3(1, 64), 256, 0, stream>>>(
        u2b, xpwb + (long)i * 48 * NDI, nullptr, dbc, 48, NDI);
    // chunked parallel scan (dt-proj + softplus fused); CHUNK=16 -> 1024 blocks
    scanA<<<BATCH * NCH * 2, 256, 0, stream>>>(u2b, dbc, dtw, dtb, al, sEnd, prodA);
    scanB<<<BATCH * NDI * NDS / 256, 256, 0, stream>>>(sEnd, prodA);  // in-place -> carry
    scanC<<<BATCH * NCH * 2, 256, 0, stream>>>(u2b, dbc, xzb, dtw, dtb, al, dd,
                                               sEnd, ybb);
    // h += yb @ out_w^T  (MFMA, 8192x256x512)
    gemm_bf16<64, false, true, false, false><<<dim3(4, 64), 256, 0, stream>>>(
        ybb, owb + (long)i * NDM * NDI, nullptr, h, NDM, NDI);
  }

  hipMemsetAsync(pooled, 0, BATCH * NDM * sizeof(float), stream);
  finalpool_k<<<TTOK / 32, 256, 0, stream>>>(h, fnorm_w, pooled);
  bias_k<<<BATCH, 128, 0, stream>>>(pooled, proj_w, proj_b, bv);
  addout_k<<<TTOK * NF / 4 / 256, 256, 0, stream>>>(x, bv, (float*)d_out);
}

// Round 8
// 289.668 us; speedup vs baseline: 11.2974x; 1.0596x over previous
//
#include <hip/hip_runtime.h>

#define TTOK 8192   // B*L
#define BATCH 4
#define LSEQ 2048
#define NDM 256
#define NF 128
#define NDI 512
#define NDS 16
#define NDR 16
#define CHUNK 16
#define NCH (LSEQ / CHUNK)   // 128
#define NCH_LOG 7

typedef unsigned short u16;
typedef __attribute__((ext_vector_type(8))) short bf16x8;
typedef __attribute__((ext_vector_type(4))) float f32x4;

__device__ __forceinline__ float sigmoidf_(float x) { return 1.f / (1.f + __expf(-x)); }

__device__ __forceinline__ u16 f2bf(float f) {  // RTN-even
  unsigned u = __float_as_uint(f);
  u += 0x7FFF + ((u >> 16) & 1);
  return (u16)(u >> 16);
}
__device__ __forceinline__ float bf2f(u16 v) {
  return __uint_as_float((unsigned)v << 16);
}
__device__ __forceinline__ float softplus_(float x) {  // stable
  return fmaxf(x, 0.f) + __logf(1.f + __expf(-fabsf(x)));
}

// ---------------- bf16 MFMA GEMM ----------------
// C = A·W^T (+bias) (+= if RES). A:[M][K] bf16, W:[N][K] bf16.
// Tile 128 x BN_T, BK=64, 4 waves (2x2). NCHK: clamp W rows / skip cols >= N.
// EPI: 0 = f32 out (RES optional). 1 = "H" epilogue: f32 out + bf16 copy (hb)
//      + per-row sum-of-squares atomicAdd into rssq (for the commuted rmsnorm).
//      2 = "RMS" epilogue: scale by rsqrt(rssq[r]/256+eps), bf16 out.
template<int BN_T, bool BIAS, bool RES, bool NCHK, int EPI>
__global__ __launch_bounds__(256) void gemm_bf16(const u16* __restrict__ A,
                                                 const u16* __restrict__ W,
                                                 const float* __restrict__ bias,
                                                 void* __restrict__ Cv,
                                                 int N, int K,
                                                 u16* __restrict__ hb,
                                                 float* __restrict__ rssq) {
  constexpr int NR = BN_T / 32;
  constexpr int ROWS = 128 + BN_T;
  constexpr int CPW = (ROWS / 8) / 4;
  __shared__ u16 lds[ROWS * 64];
  const int tid = threadIdx.x;
  const int wave = tid >> 6, lane = tid & 63;
  const int wrow = wave >> 1, wcol = wave & 1;
  const int lr = lane & 15, lg = lane >> 4;
  const int row0 = blockIdx.y * 128, col0 = blockIdx.x * BN_T;

  const u16* srcp[CPW];
  u16* ldsp[CPW];
#pragma unroll
  for (int i = 0; i < CPW; ++i) {
    const int q = wave * CPW + i;
    const int row = q * 8 + (lane >> 3);
    const int ck = lane & 7;
    const int sck = ck ^ (row & 7);
    long grow;
    if (row < 128) grow = (long)(row0 + row) * K;
    else {
      int wr = row - 128;
      if (NCHK && wr >= N) wr = N - 1;
      grow = (long)(col0 + wr) * K;
    }
    srcp[i] = ((row < 128) ? A : W) + grow + sck * 8;
    ldsp[i] = (u16*)&lds[q * 512];
  }

  int aoff[4], as7[4], boff[NR], bs7[NR];
#pragma unroll
  for (int m = 0; m < 4; ++m) {
    const int r = wrow * 64 + m * 16 + lr;
    aoff[m] = r * 64; as7[m] = r & 7;
  }
#pragma unroll
  for (int n = 0; n < NR; ++n) {
    const int r = 128 + wcol * (BN_T / 2) + n * 16 + lr;
    boff[n] = r * 64; bs7[n] = r & 7;
  }

  f32x4 acc[4][NR];
#pragma unroll
  for (int m = 0; m < 4; ++m)
#pragma unroll
    for (int n = 0; n < NR; ++n) acc[m][n] = (f32x4)(0.f);

  for (int k0 = 0; k0 < K; k0 += 64) {
#pragma unroll
    for (int i = 0; i < CPW; ++i)
      __builtin_amdgcn_global_load_lds(
          (const __attribute__((address_space(1))) unsigned int*)(srcp[i] + k0),
          (__attribute__((address_space(3))) unsigned int*)(ldsp[i]), 16, 0, 0);
    __syncthreads();

    bf16x8 af[2][4], bfr[2][NR];
#pragma unroll
    for (int kq = 0; kq < 2; ++kq) {
      const int kc = kq * 4 + lg;
#pragma unroll
      for (int m = 0; m < 4; ++m)
        af[kq][m] = *(const bf16x8*)(lds + aoff[m] + ((kc ^ as7[m]) << 3));
#pragma unroll
      for (int n = 0; n < NR; ++n)
        bfr[kq][n] = *(const bf16x8*)(lds + boff[n] + ((kc ^ bs7[n]) << 3));
    }
#pragma unroll
    for (int kq = 0; kq < 2; ++kq)
#pragma unroll
      for (int m = 0; m < 4; ++m)
#pragma unroll
        for (int n = 0; n < NR; ++n)
          acc[m][n] = __builtin_amdgcn_mfma_f32_16x16x32_bf16(af[kq][m], bfr[kq][n],
                                                              acc[m][n], 0, 0, 0);
    __syncthreads();
  }

  // C/D layout: col = lane&15, row = (lane>>4)*4 + j
#pragma unroll
  for (int m = 0; m < 4; ++m) {
    const int rbase = row0 + wrow * 64 + m * 16 + lg * 4;
#pragma unroll
    for (int j = 0; j < 4; ++j) {
      const int r = rbase + j;
      if (EPI == 2) {
        const float rs = rsqrtf(rssq[r] * (1.f / 256.f) + 1e-6f);
#pragma unroll
        for (int n = 0; n < NR; ++n) {
          const int c = col0 + wcol * (BN_T / 2) + n * 16 + lr;
          ((u16*)Cv)[(long)r * N + c] = f2bf(acc[m][n][j] * rs);
        }
      } else if (EPI == 1) {
        float ssq = 0.f;
#pragma unroll
        for (int n = 0; n < NR; ++n) {
          const int c = col0 + wcol * (BN_T / 2) + n * 16 + lr;
          float v = acc[m][n][j] + (BIAS ? bias[c] : 0.f);
          const long off = (long)r * N + c;
          if (RES) v += ((float*)Cv)[off];
          ((float*)Cv)[off] = v;
          hb[off] = f2bf(v);
          ssq = fmaf(v, v, ssq);
        }
        ssq += __shfl_xor(ssq, 1); ssq += __shfl_xor(ssq, 2);
        ssq += __shfl_xor(ssq, 4); ssq += __shfl_xor(ssq, 8);
        if (lr == 0) atomicAdd(rssq + r, ssq);
      } else {
#pragma unroll
        for (int n = 0; n < NR; ++n) {
          const int c = col0 + wcol * (BN_T / 2) + n * 16 + lr;
          if (NCHK && c >= N) continue;
          float v = acc[m][n][j] + (BIAS ? bias[c] : 0.f);
          float* p = (float*)Cv + (long)r * N + c;
          if (RES) *p += v; else *p = v;
        }
      }
    }
  }
}

// one-shot conversion of x + all weights to bf16; norm_w folded into in_w.
// vec4 counts: x 262144 | embed_w 8192 | in_w 131072 | out_w 65536 | xproj_w 12288
__global__ __launch_bounds__(256) void megacvt_k(
    const float* __restrict__ x, const float* __restrict__ ew,
    const float* __restrict__ iw, const float* __restrict__ ow,
    const float* __restrict__ xw, const float* __restrict__ nw,
    u16* __restrict__ xb, u16* __restrict__ ewb, u16* __restrict__ iwb,
    u16* __restrict__ owb, u16* __restrict__ xwb) {
  int i = blockIdx.x * 256 + threadIdx.x;
  float4 v;
  u16* d; int di;
  if (i < 262144) { v = ((const float4*)x)[i]; d = xb; di = i; }
  else if ((i -= 262144) < 8192) { v = ((const float4*)ew)[i]; d = ewb; di = i; }
  else if ((i -= 8192) < 131072) {
    v = ((const float4*)iw)[i];
    const int layer = i >> 16;                 // 65536 vec4 per layer
    const float4 g = *(const float4*)(nw + layer * NDM + ((i & 63) << 2));
    v.x *= g.x; v.y *= g.y; v.z *= g.z; v.w *= g.w;
    d = iwb; di = i;
  }
  else if ((i -= 131072) < 65536) { v = ((const float4*)ow)[i]; d = owb; di = i; }
  else { i -= 65536; v = ((const float4*)xw)[i]; d = xwb; di = i; }
  ushort4 o;
  o.x = f2bf(v.x); o.y = f2bf(v.y); o.z = f2bf(v.z); o.w = f2bf(v.w);
  ((ushort4*)d)[di] = o;
}

// u2 = silu(depthwise causal conv(u)); bf16 in/out; 4 t-rows per block
__global__ __launch_bounds__(256) void conv_silu_k(const u16* __restrict__ xzb,
                                                   const float* __restrict__ cw,
                                                   const float* __restrict__ cb,
                                                   u16* __restrict__ u2b) {
  const int t0 = blockIdx.x * 4;
  const int l0 = t0 & (LSEQ - 1);   // t0 multiple of 4, LSEQ%4==0: no wrap in 4
#pragma unroll
  for (int half = 0; half < 2; ++half) {
    const int ch = threadIdx.x + half * 256;
    const float w0 = cw[ch * 4], w1 = cw[ch * 4 + 1];
    const float w2 = cw[ch * 4 + 2], w3 = cw[ch * 4 + 3];
    const float bias = cb[ch];
    float v[7];
#pragma unroll
    for (int m = 0; m < 7; ++m) {
      const int tt = t0 - 3 + m;
      v[m] = (tt >= 0) ? bf2f(xzb[(long)tt * 1024 + ch]) : 0.f;
    }
#pragma unroll
    for (int j = 0; j < 4; ++j) {
      const int l = l0 + j;
      float acc = bias;
      if (l >= 3) acc = fmaf(v[j + 0], w0, acc);
      if (l >= 2) acc = fmaf(v[j + 1], w1, acc);
      if (l >= 1) acc = fmaf(v[j + 2], w2, acc);
      acc = fmaf(v[j + 3], w3, acc);
      u2b[(long)(t0 + j) * NDI + ch] = f2bf(acc * sigmoidf_(acc));
    }
  }
}

// ---- chunked parallel scan, thread-per-(b,c,d), 16 states in regs.
// ILP restructure: stage 1 computes dl[j]/du[j] for all CHUNK steps (independent,
// 4-partial dots -> loads prefetch); stage 2 is the recurrence (16 interleaved
// 4-cycle fma chains + independent exps = throughput-bound).

__global__ __launch_bounds__(256) void scanA(const u16* __restrict__ u2b,
                                             const float* __restrict__ dbc,
                                             const float* __restrict__ dtw,
                                             const float* __restrict__ dtbv,
                                             const float* __restrict__ Alog,
                                             float* __restrict__ sEnd,
                                             float* __restrict__ prodA) {
  const int d = ((blockIdx.x & 1) << 8) + threadIdx.x;
  const int cb = blockIdx.x >> 1;
  const int c = cb & (NCH - 1), b = cb >> NCH_LOG;
  float Ac[16], dtr[16];
#pragma unroll
  for (int q = 0; q < 4; ++q) {
    float4 v = *(const float4*)(Alog + d * NDS + q * 4);
    Ac[q * 4 + 0] = -__expf(v.x); Ac[q * 4 + 1] = -__expf(v.y);
    Ac[q * 4 + 2] = -__expf(v.z); Ac[q * 4 + 3] = -__expf(v.w);
    float4 w = *(const float4*)(dtw + d * NDR + q * 4);
    dtr[q * 4 + 0] = w.x; dtr[q * 4 + 1] = w.y; dtr[q * 4 + 2] = w.z; dtr[q * 4 + 3] = w.w;
  }
  const float dtb_d = dtbv[d];
  const int tbase = b * LSEQ + c * CHUNK;

  float dl[CHUNK], du[CHUNK];
#pragma unroll
  for (int j = 0; j < CHUNK; ++j) {
    const float* row = dbc + (long)(tbase + j) * 48;
    const float4 d0 = *(const float4*)(row);
    const float4 d1 = *(const float4*)(row + 4);
    const float4 d2 = *(const float4*)(row + 8);
    const float4 d3 = *(const float4*)(row + 12);
    const float p0 = fmaf(d0.x, dtr[0], fmaf(d1.x, dtr[4], fmaf(d2.x, dtr[8],  d3.x * dtr[12])));
    const float p1 = fmaf(d0.y, dtr[1], fmaf(d1.y, dtr[5], fmaf(d2.y, dtr[9],  d3.y * dtr[13])));
    const float p2 = fmaf(d0.z, dtr[2], fmaf(d1.z, dtr[6], fmaf(d2.z, dtr[10], d3.z * dtr[14])));
    const float p3 = fmaf(d0.w, dtr[3], fmaf(d1.w, dtr[7], fmaf(d2.w, dtr[11], d3.w * dtr[15])));
    dl[j] = softplus_(dtb_d + ((p0 + p1) + (p2 + p3)));
    du[j] = dl[j] * bf2f(u2b[(long)(tbase + j) * NDI + d]);
  }
  float dacc = 0.f;
#pragma unroll
  for (int j = 0; j < CHUNK; ++j) dacc += dl[j];

  float s[16] = {};
#pragma unroll
  for (int j = 0; j < CHUNK; ++j) {
    const float* row = dbc + (long)(tbase + j) * 48 + NDR;
    const float dlj = dl[j], duj = du[j];
#pragma unroll
    for (int q = 0; q < 4; ++q) {
      const float4 Bv = *(const float4*)(row + q * 4);
      const float Be[4] = {Bv.x, Bv.y, Bv.z, Bv.w};
#pragma unroll
      for (int e = 0; e < 4; ++e) {
        const int n = q * 4 + e;
        s[n] = fmaf(__expf(dlj * Ac[n]), s[n], duj * Be[e]);
      }
    }
  }
  const long base = ((long)((b * NCH + c) * NDI + d)) * NDS;
#pragma unroll
  for (int q = 0; q < 4; ++q) {
    *(float4*)(sEnd + base + q * 4) =
        make_float4(s[q * 4], s[q * 4 + 1], s[q * 4 + 2], s[q * 4 + 3]);
    *(float4*)(prodA + base + q * 4) =
        make_float4(__expf(Ac[q * 4] * dacc), __expf(Ac[q * 4 + 1] * dacc),
                    __expf(Ac[q * 4 + 2] * dacc), __expf(Ac[q * 4 + 3] * dacc));
  }
}

// Phase B, IN-PLACE: sp holds sEnd on entry, carry on exit (one thread per idx).
__global__ __launch_bounds__(256) void scanB(float* __restrict__ sp,
                                             const float* __restrict__ prodA) {
  const int g = blockIdx.x * 256 + threadIdx.x;   // (b, d*16+n)
  const int dn = g & (NDI * NDS - 1);
  const int b = g >> 13;
  float h = 0.f;
  const long base = (long)b * NCH * NDI * NDS + dn;
#pragma unroll 8
  for (int c = 0; c < NCH; ++c) {
    const long idx = base + (long)c * NDI * NDS;
    const float pe = sp[idx];
    const float pa = prodA[idx];
    sp[idx] = h;
    h = fmaf(pa, h, pe);
  }
}

__global__ __launch_bounds__(256) void scanC(const u16* __restrict__ u2b,
                                             const float* __restrict__ dbc,
                                             const u16* __restrict__ xzb,
                                             const float* __restrict__ dtw,
                                             const float* __restrict__ dtbv,
                                             const float* __restrict__ Alog,
                                             const float* __restrict__ Dp,
                                             const float* __restrict__ carry,
                                             u16* __restrict__ y) {
  const int d = ((blockIdx.x & 1) << 8) + threadIdx.x;
  const int cb = blockIdx.x >> 1;
  const int c = cb & (NCH - 1), b = cb >> NCH_LOG;
  float Ac[16], dtr[16];
#pragma unroll
  for (int q = 0; q < 4; ++q) {
    float4 v = *(const float4*)(Alog + d * NDS + q * 4);
    Ac[q * 4 + 0] = -__expf(v.x); Ac[q * 4 + 1] = -__expf(v.y);
    Ac[q * 4 + 2] = -__expf(v.z); Ac[q * 4 + 3] = -__expf(v.w);
    float4 w = *(const float4*)(dtw + d * NDR + q * 4);
    dtr[q * 4 + 0] = w.x; dtr[q * 4 + 1] = w.y; dtr[q * 4 + 2] = w.z; dtr[q * 4 + 3] = w.w;
  }
  const float dtb_d = dtbv[d];
  const float Dv = Dp[d];
  const int tbase = b * LSEQ + c * CHUNK;

  float dl[CHUNK], ul[CHUNK];
#pragma unroll
  for (int j = 0; j < CHUNK; ++j) {
    const float* row = dbc + (long)(tbase + j) * 48;
    const float4 d0 = *(const float4*)(row);
    const float4 d1 = *(const float4*)(row + 4);
    const float4 d2 = *(const float4*)(row + 8);
    const float4 d3 = *(const float4*)(row + 12);
    const float p0 = fmaf(d0.x, dtr[0], fmaf(d1.x, dtr[4], fmaf(d2.x, dtr[8],  d3.x * dtr[12])));
    const float p1 = fmaf(d0.y, dtr[1], fmaf(d1.y, dtr[5], fmaf(d2.y, dtr[9],  d3.y * dtr[13])));
    const float p2 = fmaf(d0.z, dtr[2], fmaf(d1.z, dtr[6], fmaf(d2.z, dtr[10], d3.z * dtr[14])));
    const float p3 = fmaf(d0.w, dtr[3], fmaf(d1.w, dtr[7], fmaf(d2.w, dtr[11], d3.w * dtr[15])));
    dl[j] = softplus_(dtb_d + ((p0 + p1) + (p2 + p3)));
    ul[j] = bf2f(u2b[(long)(tbase + j) * NDI + d]);
  }

  float s[16];
  const long base = ((long)((b * NCH + c) * NDI + d)) * NDS;
#pragma unroll
  for (int q = 0; q < 4; ++q) {
    float4 v = *(const float4*)(carry + base + q * 4);
    s[q * 4 + 0] = v.x; s[q * 4 + 1] = v.y; s[q * 4 + 2] = v.z; s[q * 4 + 3] = v.w;
  }
#pragma unroll
  for (int j = 0; j < CHUNK; ++j) {
    const int t = tbase + j;
    const float* row = dbc + (long)t * 48 + NDR;
    const float dlj = dl[j];
    const float duj = dlj * ul[j];
    float pp[4];
#pragma unroll
    for (int q = 0; q < 4; ++q) {
      const float4 Bv = *(const float4*)(row + q * 4);
      const float4 Cq = *(const float4*)(row + NDS + q * 4);
      const float Be[4] = {Bv.x, Bv.y, Bv.z, Bv.w};
      const float Ce[4] = {Cq.x, Cq.y, Cq.z, Cq.w};
      float p = 0.f;
#pragma unroll
      for (int e = 0; e < 4; ++e) {
        const int n = q * 4 + e;
        s[n] = fmaf(__expf(dlj * Ac[n]), s[n], duj * Be[e]);
        p = fmaf(s[n], Ce[e], p);
      }
      pp[q] = p;
    }
    const float p = (pp[0] + pp[1]) + (pp[2] + pp[3]);
    const float zl = bf2f(xzb[(long)t * 1024 + NDI + d]);
    y[(long)t * NDI + d] = f2bf((p + ul[j] * Dv) * zl * sigmoidf_(zl));
  }
}

// fused final rmsnorm + mean-pool: block = 32 rows, wave per row (4 elems/lane)
__global__ __launch_bounds__(256) void finalpool_k(const float* __restrict__ h,
                                                   const float* __restrict__ w,
                                                   float* __restrict__ pooled) {
  const int wave = threadIdx.x >> 6, lane = threadIdx.x & 63;
  const int t0 = blockIdx.x * 32;
  const int b = t0 >> 11;
  const float4 wv = ((const float4*)w)[lane];
  float a0 = 0.f, a1 = 0.f, a2 = 0.f, a3 = 0.f;
  for (int r = wave; r < 32; r += 4) {
    const float4 v = ((const float4*)(h + (long)(t0 + r) * NDM))[lane];
    float ss = v.x * v.x + v.y * v.y + v.z * v.z + v.w * v.w;
#pragma unroll
    for (int off = 32; off >= 1; off >>= 1) ss += __shfl_xor(ss, off);
    const float rs = rsqrtf(ss * (1.f / NDM) + 1e-6f);
    a0 = fmaf(v.x * rs, wv.x, a0); a1 = fmaf(v.y * rs, wv.y, a1);
    a2 = fmaf(v.z * rs, wv.z, a2); a3 = fmaf(v.w * rs, wv.w, a3);
  }
  __shared__ float red[4][NDM];
  red[wave][lane * 4 + 0] = a0; red[wave][lane * 4 + 1] = a1;
  red[wave][lane * 4 + 2] = a2; red[wave][lane * 4 + 3] = a3;
  __syncthreads();
  if (wave == 0) {
#pragma unroll
    for (int e = 0; e < 4; ++e) {
      const int dc = lane * 4 + e;
      const float sum = red[0][dc] + red[1][dc] + red[2][dc] + red[3][dc];
      atomicAdd(pooled + b * NDM + dc, sum * (1.f / LSEQ));
    }
  }
}

__global__ __launch_bounds__(128) void bias_k(const float* __restrict__ pooled,
                                              const float* __restrict__ pw,
                                              const float* __restrict__ pb,
                                              float* __restrict__ bv) {
  const int b = blockIdx.x, f = threadIdx.x;
  float acc = pb[f];
  for (int dd = 0; dd < NDM; ++dd) acc = fmaf(pooled[b * NDM + dd], pw[f * NDM + dd], acc);
  bv[b * NF + f] = acc;
}

__global__ __launch_bounds__(256) void addout_k(const float* __restrict__ x,
                                                const float* __restrict__ bv,
                                                float* __restrict__ out) {
  const int i4 = blockIdx.x * 256 + threadIdx.x;
  const float4 xv = ((const float4*)x)[i4];
  const int trow = i4 >> 5;
  const int b = trow >> 11;
  const int f4 = i4 & 31;
  const float4 bb = ((const float4*)bv)[b * 32 + f4];
  float4 o;
  o.x = xv.x + bb.x; o.y = xv.y + bb.y; o.z = xv.z + bb.z; o.w = xv.w + bb.w;
  ((float4*)out)[i4] = o;
}

extern "C" void kernel_launch(void* const* d_in, const int* in_sizes, int n_in,
                              void* d_out, int out_size, void* d_ws, size_t ws_size,
                              hipStream_t stream) {
  const float* x       = (const float*)d_in[0];
  const float* embed_w = (const float*)d_in[1];
  const float* embed_b = (const float*)d_in[2];
  const float* in_w    = (const float*)d_in[3];
  const float* conv_w  = (const float*)d_in[4];
  const float* conv_b  = (const float*)d_in[5];
  const float* xproj_w = (const float*)d_in[6];
  const float* dt_w    = (const float*)d_in[7];
  const float* dt_b    = (const float*)d_in[8];
  const float* A_log   = (const float*)d_in[9];
  const float* Dw      = (const float*)d_in[10];
  const float* out_w   = (const float*)d_in[11];
  const float* norm_w  = (const float*)d_in[12];
  const float* fnorm_w = (const float*)d_in[13];
  const float* proj_w  = (const float*)d_in[14];
  const float* proj_b  = (const float*)d_in[15];

  // workspace layout (f32 units), ~85.2 MB (ws >= 97.5 MB proven R1-3).
  // Full audit, all bf16 buffers sized exactly (R4 lesson).
  float* ws      = (float*)d_ws;
  float* h       = ws;                     // 2,097,152 f32
  float* hbr     = h    + 2097152;         // 1,048,576 f32-eq: hb bf16 (2M elems)
  float* xzr     = hbr  + 1048576;         // 4,194,304 f32-eq: xzb bf16 (8M elems)
  float* u2r     = xzr  + 4194304;         // 2,097,152 f32-eq: u2b bf16 (4M elems)
  float* ybr     = u2r  + 2097152;         // 2,097,152 f32-eq: ybb bf16 (4M elems)
  float* dbc     = ybr  + 2097152;         // 393,216 f32
  float* sEnd    = dbc  + 393216;          // 4,194,304 f32 (becomes carry in-place)
  float* prodA   = sEnd + 4194304;         // 4,194,304 f32
  float* xbr     = prodA + 4194304;        // 524,288 f32-eq: xb bf16 (1M elems)
  float* inwr    = xbr  + 524288;          // 262,144 f32-eq: in_w' bf16 (both layers)
  float* owr     = inwr + 262144;          // 131,072 f32-eq: out_w bf16
  float* xpwr    = owr  + 131072;          // 24,576 f32-eq: xproj_w bf16
  float* ewr     = xpwr + 24576;           // 16,384 f32-eq: embed_w bf16
  float* pooled  = ewr  + 16384;           // 1,024
  float* rowssq0 = pooled + 1024;          // 8,192
  float* rowssq1 = rowssq0 + 8192;         // 8,192
  float* bv      = rowssq1 + 8192;         // 512

  u16* ybb  = (u16*)ybr;
  u16* hb   = (u16*)hbr;
  u16* xzb  = (u16*)xzr;
  u16* u2b  = (u16*)u2r;
  u16* xb   = (u16*)xbr;
  u16* inwb = (u16*)inwr;
  u16* owb  = (u16*)owr;
  u16* xpwb = (u16*)xpwr;
  u16* ewb  = (u16*)ewr;

  // one-shot bf16 conversion (norm_w folded into in_w); zero pooled+rowssq
  megacvt_k<<<1872, 256, 0, stream>>>(x, embed_w, in_w, out_w, xproj_w, norm_w,
                                      xb, ewb, inwb, owb, xpwb);
  hipMemsetAsync(pooled, 0, (1024 + 2 * 8192) * sizeof(float), stream);

  // h = x @ embed_w^T + embed_b   (MFMA; H-epilogue -> h, hb, rowssq0)
  gemm_bf16<64, true, false, false, 1><<<dim3(4, 64), 256, 0, stream>>>(
      xb, ewb, embed_b, h, NDM, NF, hb, rowssq0);

  for (int i = 0; i < 2; ++i) {
    const float* cw  = conv_w + (long)i * NDI * 4;
    const float* cb  = conv_b + (long)i * NDI;
    const float* dtw = dt_w   + (long)i * NDI * NDR;
    const float* dtb = dt_b   + (long)i * NDI;
    const float* al  = A_log  + (long)i * NDI * NDS;
    const float* dd  = Dw     + (long)i * NDI;
    float* rsq       = i ? rowssq1 : rowssq0;

    // xz = rmsnorm(h) @ in_w'^T  (commuted: RMS epilogue scales by rsqrt(rowssq))
    gemm_bf16<128, false, false, false, 2><<<dim3(8, 64), 256, 0, stream>>>(
        hb, inwb + (long)i * 2 * NDI * NDM, nullptr, xzb, 1024, NDM, nullptr, rsq);
    conv_silu_k<<<TTOK / 4, 256, 0, stream>>>(xzb, cw, cb, u2b);
    // dbc = u2 @ xproj_w^T  (MFMA, N=48 clamped)
    gemm_bf16<64, false, false, true, 0><<<dim3(1, 64), 256, 0, stream>>>(
        u2b, xpwb + (long)i * 48 * NDI, nullptr, dbc, 48, NDI, nullptr, nullptr);
    // chunked parallel scan (dt-proj + softplus fused, ILP-restructured)
    scanA<<<BATCH * NCH * 2, 256, 0, stream>>>(u2b, dbc, dtw, dtb, al, sEnd, prodA);
    scanB<<<BATCH * NDI * NDS / 256, 256, 0, stream>>>(sEnd, prodA);  // in-place
    scanC<<<BATCH * NCH * 2, 256, 0, stream>>>(u2b, dbc, xzb, dtw, dtb, al, dd,
                                               sEnd, ybb);
    // h += yb @ out_w^T; layer 0 gets H-epilogue (feeds layer 1), layer 1 plain
    if (i == 0)
      gemm_bf16<64, false, true, false, 1><<<dim3(4, 64), 256, 0, stream>>>(
          ybb, owb, nullptr, h, NDM, NDI, hb, rowssq1);
    else
      gemm_bf16<64, false, true, false, 0><<<dim3(4, 64), 256, 0, stream>>>(
          ybb, owb + (long)NDM * NDI, nullptr, h, NDM, NDI, nullptr, nullptr);
  }

  finalpool_k<<<TTOK / 32, 256, 0, stream>>>(h, fnorm_w, pooled);
  bias_k<<<BATCH, 128, 0, stream>>>(pooled, proj_w, proj_b, bv);
  addout_k<<<TTOK * NF / 4 / 256, 256, 0, stream>>>(x, bv, (float*)d_out);
}